// Round 12
// baseline (258.931 us; speedup 1.0000x reference)
//
#include <hip/hip_runtime.h>
#include <hip/hip_fp16.h>
#include <math.h>

#define D_IN 128
#define D_H  64
#define D_OUT 40
#define NEG_SLOPE 0.2f

// ---------------- CSR build ----------------

__global__ void k_count(const int* __restrict__ ei, int E, int N, int* __restrict__ deg) {
    int e = blockIdx.x * blockDim.x + threadIdx.x;
    int EP = E + N;
    if (e >= EP) return;
    int d = (e < E) ? ei[E + e] : (e - E);
    atomicAdd(&deg[d], 1);
}

__global__ __launch_bounds__(256) void k_scan1(const int* __restrict__ deg, int N,
                                               int* __restrict__ offs, int* __restrict__ bsums) {
    int t = threadIdx.x;
    int i = blockIdx.x * 256 + t;
    int lane = t & 63, w = t >> 6;
    int v = (i < N) ? deg[i] : 0;
    int incl = v;
    for (int o = 1; o < 64; o <<= 1) {
        int n = __shfl_up(incl, o);
        if (lane >= o) incl += n;
    }
    __shared__ int wsum[4];
    if (lane == 63) wsum[w] = incl;
    __syncthreads();
    int woff = 0;
    for (int j = 0; j < w; j++) woff += wsum[j];
    if (i < N) offs[i] = woff + incl - v;
    if (t == 255) bsums[blockIdx.x] = woff + incl;
}

__global__ __launch_bounds__(256) void k_scan2(const int* __restrict__ bsums, int nb,
                                               int* __restrict__ boffs) {
    int t = threadIdx.x;
    int lane = t & 63, w = t >> 6;
    int v = (t < nb) ? bsums[t] : 0;
    int incl = v;
    for (int o = 1; o < 64; o <<= 1) {
        int n = __shfl_up(incl, o);
        if (lane >= o) incl += n;
    }
    __shared__ int wsum[4];
    if (lane == 63) wsum[w] = incl;
    __syncthreads();
    int woff = 0;
    for (int j = 0; j < w; j++) woff += wsum[j];
    boffs[t] = woff + incl - v;
}

__global__ __launch_bounds__(256) void k_scan3(int* __restrict__ offs, const int* __restrict__ boffs,
                                               int N, int EP) {
    int i = blockIdx.x * 256 + threadIdx.x;
    if (i < N) offs[i] += boffs[blockIdx.x];
    if (i == 0) offs[N] = EP;
}

// fill CSR: single 8B non-temporal scatter per edge: ep[slot] = {src, p1}.
// nt store = no-allocate in L2 -> avoids full-line dirty writeback per edge.
__global__ void k_fill(const int* __restrict__ ei, int E, int N,
                       const int* __restrict__ offs, int* __restrict__ cursor,
                       const float* __restrict__ as1, const float* __restrict__ ad1,
                       int2* __restrict__ ep) {
    int e = blockIdx.x * blockDim.x + threadIdx.x;
    int EP = E + N;
    if (e >= EP) return;
    int s, d;
    if (e < E) { s = ei[e]; d = ei[E + e]; }
    else       { s = e - E; d = e - E; }
    int pos = atomicAdd(&cursor[d], 1);
    int slot = offs[d] + pos;
    float v = as1[s] + ad1[d];
    v = v > 0.f ? v : NEG_SLOPE * v;
    unsigned int pbits = (unsigned int)__float_as_int(__expf(v));
    long long pk = ((long long)pbits << 32) | (unsigned int)s;   // .x=s (low), .y=p (high)
    __builtin_nontemporal_store(pk, (long long*)&ep[slot]);
}

// ---------------- Layer 1 GEMM: 64x64 tile, 4x4 micro-tile, fused att dots ----

__global__ __launch_bounds__(256, 4) void k_gemm1(const float* __restrict__ x,
                                                  const float* __restrict__ W1,
                                                  const float* __restrict__ att_s,
                                                  const float* __restrict__ att_d,
                                                  int N,
                                                  __half* __restrict__ h1h,
                                                  float* __restrict__ as1,
                                                  float* __restrict__ ad1) {
    __shared__ float Wl[D_IN * D_H];
    __shared__ float xs[64 * 68];
    int t = threadIdx.x;
    for (int i = t * 4; i < D_IN * D_H; i += 1024)
        *(float4*)&Wl[i] = *(const float4*)&W1[i];

    int nodeBase = blockIdx.x * 64;
    int r0 = (t >> 4) * 4;
    int c0 = (t & 15) * 4;
    float acc[4][4] = {};

    for (int half_ = 0; half_ < 2; ++half_) {
        __syncthreads();
        for (int i = 0; i < 4; ++i) {
            int idx = i * 1024 + t * 4;
            int row = idx >> 6, col = idx & 63;
            int node = nodeBase + row;
            float4 v = make_float4(0.f, 0.f, 0.f, 0.f);
            if (node < N) v = *(const float4*)&x[node * D_IN + half_ * 64 + col];
            *(float4*)&xs[row * 68 + col] = v;
        }
        __syncthreads();
#pragma unroll 4
        for (int k4 = 0; k4 < 64; k4 += 4) {
            float4 a[4], w[4];
#pragma unroll
            for (int r = 0; r < 4; ++r) a[r] = *(float4*)&xs[(r0 + r) * 68 + k4];
#pragma unroll
            for (int kk = 0; kk < 4; ++kk) w[kk] = *(float4*)&Wl[(half_ * 64 + k4 + kk) * D_H + c0];
#pragma unroll
            for (int r = 0; r < 4; ++r) {
                const float* av = (const float*)&a[r];
#pragma unroll
                for (int kk = 0; kk < 4; ++kk) {
                    acc[r][0] = fmaf(av[kk], w[kk].x, acc[r][0]);
                    acc[r][1] = fmaf(av[kk], w[kk].y, acc[r][1]);
                    acc[r][2] = fmaf(av[kk], w[kk].z, acc[r][2]);
                    acc[r][3] = fmaf(av[kk], w[kk].w, acc[r][3]);
                }
            }
        }
    }

#pragma unroll
    for (int r = 0; r < 4; ++r) {
        int node = nodeBase + r0 + r;
        if (node < N) {
            union { __half2 h2v[2]; uint2 u; } pk;
            pk.h2v[0] = __floats2half2_rn(acc[r][0], acc[r][1]);
            pk.h2v[1] = __floats2half2_rn(acc[r][2], acc[r][3]);
            *(uint2*)&h1h[(size_t)node * D_H + c0] = pk.u;
        }
    }
    float4 as4 = *(const float4*)&att_s[c0];
    float4 ad4 = *(const float4*)&att_d[c0];
    float ps[4], pd[4];
#pragma unroll
    for (int r = 0; r < 4; ++r) {
        ps[r] = acc[r][0] * as4.x + acc[r][1] * as4.y + acc[r][2] * as4.z + acc[r][3] * as4.w;
        pd[r] = acc[r][0] * ad4.x + acc[r][1] * ad4.y + acc[r][2] * ad4.z + acc[r][3] * ad4.w;
    }
#pragma unroll
    for (int o = 1; o < 16; o <<= 1) {
#pragma unroll
        for (int r = 0; r < 4; ++r) {
            ps[r] += __shfl_xor(ps[r], o);
            pd[r] += __shfl_xor(pd[r], o);
        }
    }
    if ((t & 15) == 0) {
#pragma unroll
        for (int r = 0; r < 4; ++r) {
            int node = nodeBase + r0 + r;
            if (node < N) { as1[node] = ps[r]; ad1[node] = pd[r]; }
        }
    }
}

// ---- Layer 1 aggregation: reg-cached (s,p), shfl-fed gathers, 2x unroll ----

__global__ __launch_bounds__(256) void k_agg1(const int* __restrict__ offs,
                                              const int2* __restrict__ ep,
                                              const __half* __restrict__ h1h,
                                              const float* __restrict__ b1,
                                              int N,
                                              __half* __restrict__ agg1h) {
    int t = threadIdx.x;
    int wave = t >> 6, lane = t & 63;
    int node = blockIdx.x * 4 + wave;
    if (node >= N) return;
    int start = offs[node], end = offs[node + 1];
    int cnt = end - start;

    int sv = 0; float pv = 0.f;
    if (lane < cnt) { int2 v = ep[start + lane]; sv = v.x; pv = __int_as_float(v.y); }
    float ss = pv;
    for (int i = start + 64 + lane; i < end; i += 64) ss += __int_as_float(ep[i].y);
#pragma unroll
    for (int o = 32; o >= 1; o >>= 1) ss += __shfl_xor(ss, o);
    float inv = 1.f / (ss + 1e-16f);

    int g = lane >> 4;
    int l = lane & 15;
    int mainc = cnt < 64 ? cnt : 64;
    float4 acc0 = make_float4(0.f, 0.f, 0.f, 0.f);
    float4 acc1 = make_float4(0.f, 0.f, 0.f, 0.f);
    for (int j = 0; j < mainc; j += 8) {
        int i0 = j + g, i1 = j + 4 + g;
        bool v0 = i0 < mainc, v1 = i1 < mainc;
        int s0 = __shfl(sv, v0 ? i0 : 0);
        int s1 = __shfl(sv, v1 ? i1 : 0);
        float p0 = __shfl(pv, v0 ? i0 : 0); p0 = v0 ? p0 : 0.f;
        float p1 = __shfl(pv, v1 ? i1 : 0); p1 = v1 ? p1 : 0.f;
        uint2 r0 = *(const uint2*)&h1h[(size_t)s0 * D_H + l * 4];
        uint2 r1 = *(const uint2*)&h1h[(size_t)s1 * D_H + l * 4];
        float2 a0 = __half22float2(*(__half2*)&r0.x);
        float2 b0 = __half22float2(*(__half2*)&r0.y);
        float2 a1 = __half22float2(*(__half2*)&r1.x);
        float2 b1f = __half22float2(*(__half2*)&r1.y);
        acc0.x = fmaf(p0, a0.x, acc0.x); acc0.y = fmaf(p0, a0.y, acc0.y);
        acc0.z = fmaf(p0, b0.x, acc0.z); acc0.w = fmaf(p0, b0.y, acc0.w);
        acc1.x = fmaf(p1, a1.x, acc1.x); acc1.y = fmaf(p1, a1.y, acc1.y);
        acc1.z = fmaf(p1, b1f.x, acc1.z); acc1.w = fmaf(p1, b1f.y, acc1.w);
    }
    for (int j = 64; j < cnt; j += 4) {
        int idx = start + j + g;
        int s = 0; float p = 0.f;
        if (j + g < cnt) { int2 v = ep[idx]; s = v.x; p = __int_as_float(v.y); }
        uint2 r = *(const uint2*)&h1h[(size_t)s * D_H + l * 4];
        float2 a = __half22float2(*(__half2*)&r.x);
        float2 b = __half22float2(*(__half2*)&r.y);
        acc0.x = fmaf(p, a.x, acc0.x); acc0.y = fmaf(p, a.y, acc0.y);
        acc0.z = fmaf(p, b.x, acc0.z); acc0.w = fmaf(p, b.y, acc0.w);
    }
    acc0.x += acc1.x; acc0.y += acc1.y; acc0.z += acc1.z; acc0.w += acc1.w;
#pragma unroll
    for (int o = 16; o <= 32; o <<= 1) {
        acc0.x += __shfl_xor(acc0.x, o);
        acc0.y += __shfl_xor(acc0.y, o);
        acc0.z += __shfl_xor(acc0.z, o);
        acc0.w += __shfl_xor(acc0.w, o);
    }
    if (g == 0) {
        float4 bv = *(const float4*)&b1[l * 4];
        float rx = fmaf(acc0.x, inv, bv.x); rx = rx > 0.f ? rx : 0.f;
        float ry = fmaf(acc0.y, inv, bv.y); ry = ry > 0.f ? ry : 0.f;
        float rz = fmaf(acc0.z, inv, bv.z); rz = rz > 0.f ? rz : 0.f;
        float rw = fmaf(acc0.w, inv, bv.w); rw = rw > 0.f ? rw : 0.f;
        union { __half2 h2v[2]; uint2 u; } pk;
        pk.h2v[0] = __floats2half2_rn(rx, ry);
        pk.h2v[1] = __floats2half2_rn(rz, rw);
        *(uint2*)&agg1h[(size_t)node * D_H + l * 4] = pk.u;
    }
}

// ---- Layer 2 GEMM: 64x40 tile, reads agg1 fp16, writes h2 fp16 + att dots ---

__global__ __launch_bounds__(256, 4) void k_gemm2t(const __half* __restrict__ agg1h,
                                                   const float* __restrict__ W2,
                                                   const float* __restrict__ atts2,
                                                   const float* __restrict__ attd2,
                                                   int N,
                                                   __half* __restrict__ h2h,
                                                   float* __restrict__ as2,
                                                   float* __restrict__ ad2) {
    __shared__ float Wl[D_H * D_OUT];
    __shared__ float xs[64 * 68];
    __shared__ float sps[64][10];
    __shared__ float spd[64][10];
    int t = threadIdx.x;
    for (int i = t * 4; i < D_H * D_OUT; i += 1024)
        *(float4*)&Wl[i] = *(const float4*)&W2[i];

    int nodeBase = blockIdx.x * 64;
    for (int i = 0; i < 4; ++i) {
        int idx = i * 1024 + t * 4;
        int row = idx >> 6, col = idx & 63;
        int node = nodeBase + row;
        float4 v = make_float4(0.f, 0.f, 0.f, 0.f);
        if (node < N) {
            uint2 raw = *(const uint2*)&agg1h[(size_t)node * D_H + col];
            float2 f0 = __half22float2(*(__half2*)&raw.x);
            float2 f1 = __half22float2(*(__half2*)&raw.y);
            v = make_float4(f0.x, f0.y, f1.x, f1.y);
        }
        *(float4*)&xs[row * 68 + col] = v;
    }
    __syncthreads();

    int r0 = (t / 10) * 4;
    int c0 = (t % 10) * 4;
    if (t < 160) {
        float acc[4][4] = {};
#pragma unroll 4
        for (int k4 = 0; k4 < 64; k4 += 4) {
            float4 a[4], w[4];
#pragma unroll
            for (int r = 0; r < 4; ++r) a[r] = *(float4*)&xs[(r0 + r) * 68 + k4];
#pragma unroll
            for (int kk = 0; kk < 4; ++kk) w[kk] = *(float4*)&Wl[(k4 + kk) * D_OUT + c0];
#pragma unroll
            for (int r = 0; r < 4; ++r) {
                const float* av = (const float*)&a[r];
#pragma unroll
                for (int kk = 0; kk < 4; ++kk) {
                    acc[r][0] = fmaf(av[kk], w[kk].x, acc[r][0]);
                    acc[r][1] = fmaf(av[kk], w[kk].y, acc[r][1]);
                    acc[r][2] = fmaf(av[kk], w[kk].z, acc[r][2]);
                    acc[r][3] = fmaf(av[kk], w[kk].w, acc[r][3]);
                }
            }
        }
#pragma unroll
        for (int r = 0; r < 4; ++r) {
            int node = nodeBase + r0 + r;
            if (node < N) {
                union { __half2 h2v[2]; uint2 u; } pk;
                pk.h2v[0] = __floats2half2_rn(acc[r][0], acc[r][1]);
                pk.h2v[1] = __floats2half2_rn(acc[r][2], acc[r][3]);
                *(uint2*)&h2h[(size_t)node * D_OUT + c0] = pk.u;
            }
        }
        float4 as4 = *(const float4*)&atts2[c0];
        float4 ad4 = *(const float4*)&attd2[c0];
#pragma unroll
        for (int r = 0; r < 4; ++r) {
            sps[r0 + r][t % 10] = acc[r][0] * as4.x + acc[r][1] * as4.y
                                + acc[r][2] * as4.z + acc[r][3] * as4.w;
            spd[r0 + r][t % 10] = acc[r][0] * ad4.x + acc[r][1] * ad4.y
                                + acc[r][2] * ad4.z + acc[r][3] * ad4.w;
        }
    }
    __syncthreads();
    if (t < 64) {
        int node = nodeBase + t;
        if (node < N) {
            float ps = 0.f, pd = 0.f;
#pragma unroll
            for (int j = 0; j < 10; ++j) { ps += sps[t][j]; pd += spd[t][j]; }
            as2[node] = ps; ad2[node] = pd;
        }
    }
}

// ---- Layer 2 aggregation: reg-cached (s,p2), shfl-fed gathers + log_softmax -

__global__ __launch_bounds__(256) void k_agg2(const int* __restrict__ offs,
                                              const int2* __restrict__ ep,
                                              const float* __restrict__ as2,
                                              const float* __restrict__ ad2,
                                              const __half* __restrict__ h2h,
                                              const float* __restrict__ b2,
                                              int N,
                                              float* __restrict__ out) {
    int t = threadIdx.x;
    int wave = t >> 6, lane = t & 63;
    int node = blockIdx.x * 4 + wave;
    if (node >= N) return;
    int start = offs[node], end = offs[node + 1];
    int cnt = end - start;
    float adn = ad2[node];

    int sv = 0; float pv = 0.f;
    if (lane < cnt) {
        sv = ep[start + lane].x;
        float e = as2[sv] + adn;
        e = e > 0.f ? e : NEG_SLOPE * e;
        pv = __expf(e);
    }
    float ss = pv;
    for (int i = start + 64 + lane; i < end; i += 64) {
        int s = ep[i].x;
        float e = as2[s] + adn;
        e = e > 0.f ? e : NEG_SLOPE * e;
        ss += __expf(e);
    }
#pragma unroll
    for (int o = 32; o >= 1; o >>= 1) ss += __shfl_xor(ss, o);
    float inv = 1.f / (ss + 1e-16f);

    int g = lane >> 4;
    int l = lane & 15;
    int cl = (l < 10 ? l : 9) * 4;
    int mainc = cnt < 64 ? cnt : 64;
    float4 acc0 = make_float4(0.f, 0.f, 0.f, 0.f);
    float4 acc1 = make_float4(0.f, 0.f, 0.f, 0.f);
    for (int j = 0; j < mainc; j += 8) {
        int i0 = j + g, i1 = j + 4 + g;
        bool v0 = i0 < mainc, v1 = i1 < mainc;
        int s0 = __shfl(sv, v0 ? i0 : 0);
        int s1 = __shfl(sv, v1 ? i1 : 0);
        float p0 = __shfl(pv, v0 ? i0 : 0); p0 = v0 ? p0 : 0.f;
        float p1 = __shfl(pv, v1 ? i1 : 0); p1 = v1 ? p1 : 0.f;
        uint2 r0 = *(const uint2*)&h2h[(size_t)s0 * D_OUT + cl];
        uint2 r1 = *(const uint2*)&h2h[(size_t)s1 * D_OUT + cl];
        float2 a0 = __half22float2(*(__half2*)&r0.x);
        float2 b0 = __half22float2(*(__half2*)&r0.y);
        float2 a1 = __half22float2(*(__half2*)&r1.x);
        float2 b1f = __half22float2(*(__half2*)&r1.y);
        acc0.x = fmaf(p0, a0.x, acc0.x); acc0.y = fmaf(p0, a0.y, acc0.y);
        acc0.z = fmaf(p0, b0.x, acc0.z); acc0.w = fmaf(p0, b0.y, acc0.w);
        acc1.x = fmaf(p1, a1.x, acc1.x); acc1.y = fmaf(p1, a1.y, acc1.y);
        acc1.z = fmaf(p1, b1f.x, acc1.z); acc1.w = fmaf(p1, b1f.y, acc1.w);
    }
    for (int j = 64; j < cnt; j += 4) {
        int idx = start + j + g;
        int s = 0; float p = 0.f;
        if (j + g < cnt) {
            s = ep[idx].x;
            float e = as2[s] + adn;
            e = e > 0.f ? e : NEG_SLOPE * e;
            p = __expf(e);
        }
        uint2 r = *(const uint2*)&h2h[(size_t)s * D_OUT + cl];
        float2 a = __half22float2(*(__half2*)&r.x);
        float2 b = __half22float2(*(__half2*)&r.y);
        acc0.x = fmaf(p, a.x, acc0.x); acc0.y = fmaf(p, a.y, acc0.y);
        acc0.z = fmaf(p, b.x, acc0.z); acc0.w = fmaf(p, b.y, acc0.w);
    }
    acc0.x += acc1.x; acc0.y += acc1.y; acc0.z += acc1.z; acc0.w += acc1.w;
#pragma unroll
    for (int o = 16; o <= 32; o <<= 1) {
        acc0.x += __shfl_xor(acc0.x, o);
        acc0.y += __shfl_xor(acc0.y, o);
        acc0.z += __shfl_xor(acc0.z, o);
        acc0.w += __shfl_xor(acc0.w, o);
    }

    float o0 = -INFINITY, o1 = -INFINITY, o2 = -INFINITY, o3 = -INFINITY;
    if (l < 10) {
        float4 bv = *(const float4*)&b2[l * 4];
        o0 = fmaf(acc0.x, inv, bv.x);
        o1 = fmaf(acc0.y, inv, bv.y);
        o2 = fmaf(acc0.z, inv, bv.z);
        o3 = fmaf(acc0.w, inv, bv.w);
    }
    float mm = fmaxf(fmaxf(o0, o1), fmaxf(o2, o3));
#pragma unroll
    for (int o = 1; o < 16; o <<= 1) mm = fmaxf(mm, __shfl_xor(mm, o));
    float ex = 0.f;
    if (l < 10) ex = __expf(o0 - mm) + __expf(o1 - mm) + __expf(o2 - mm) + __expf(o3 - mm);
#pragma unroll
    for (int o = 1; o < 16; o <<= 1) ex += __shfl_xor(ex, o);
    float lse = mm + logf(ex);
    if (g == 0 && l < 10) {
        float4 v = make_float4(o0 - lse, o1 - lse, o2 - lse, o3 - lse);
        *(float4*)&out[(size_t)node * D_OUT + l * 4] = v;
    }
}

// ---------------- launch ----------------

extern "C" void kernel_launch(void* const* d_in, const int* in_sizes, int n_in,
                              void* d_out, int out_size, void* d_ws, size_t ws_size,
                              hipStream_t stream) {
    const float* x     = (const float*)d_in[0];
    const int*   ei    = (const int*)d_in[1];
    const float* W1    = (const float*)d_in[2];
    const float* atts1 = (const float*)d_in[3];
    const float* attd1 = (const float*)d_in[4];
    const float* b1    = (const float*)d_in[5];
    const float* W2    = (const float*)d_in[6];
    const float* atts2 = (const float*)d_in[7];
    const float* attd2 = (const float*)d_in[8];
    const float* b2    = (const float*)d_in[9];
    float* out = (float*)d_out;

    const int N  = in_sizes[0] / D_IN;      // 50000
    const int E  = in_sizes[1] / 2;         // 800000
    const int EP = E + N;
    const int NB = (N + 255) / 256;

    char* pws = (char*)d_ws;
    int* bufA     = (int*)pws;        pws += (size_t)N * 4;        // deg, later as2
    int* bufB     = (int*)pws;        pws += (size_t)N * 4;        // cursor, later ad2
    int* offs     = (int*)pws;        pws += (size_t)(N + 2) * 4;
    int* bsums    = (int*)pws;        pws += (size_t)256 * 4;
    int* boffs    = (int*)pws;        pws += (size_t)256 * 4;
    int2* ep      = (int2*)pws;       pws += (size_t)EP * 8;       // packed {src, p1}
    __half* h1h   = (__half*)pws;     pws += (size_t)N * D_H * 2;
    float* as1    = (float*)pws;      pws += (size_t)N * 4;
    float* ad1    = (float*)pws;      pws += (size_t)N * 4;
    __half* agg1h = (__half*)pws;     pws += (size_t)N * D_H * 2;
    __half* h2h   = (__half*)pws;     pws += (size_t)N * D_OUT * 2;

    int* deg = bufA;
    int* cursor = bufB;
    float* as2 = (float*)bufA;   // deg dead after scan
    float* ad2 = (float*)bufB;   // cursor dead after fill

    hipMemsetAsync(deg, 0, (size_t)2 * N * 4, stream);

    dim3 blk(256);
    dim3 grdE((EP + 255) / 256);
    dim3 grdN((N + 3) / 4);
    dim3 grdT((N + 63) / 64);

    k_count<<<grdE, blk, 0, stream>>>(ei, E, N, deg);
    k_scan1<<<dim3(NB), blk, 0, stream>>>(deg, N, offs, bsums);
    k_scan2<<<dim3(1), blk, 0, stream>>>(bsums, NB, boffs);
    k_scan3<<<dim3(NB), blk, 0, stream>>>(offs, boffs, N, EP);

    k_gemm1<<<grdT, blk, 0, stream>>>(x, W1, atts1, attd1, N, h1h, as1, ad1);
    k_fill<<<grdE, blk, 0, stream>>>(ei, E, N, offs, cursor, as1, ad1, ep);
    k_agg1<<<grdN, blk, 0, stream>>>(offs, ep, h1h, b1, N, agg1h);
    k_gemm2t<<<grdT, blk, 0, stream>>>(agg1h, W2, atts2, attd2, N, h2h, as2, ad2);
    k_agg2<<<grdN, blk, 0, stream>>>(offs, ep, as2, ad2, h2h, b2, N, out);
}

// Round 13
// 251.983 us; speedup vs baseline: 1.0276x; 1.0276x over previous
//
#include <hip/hip_runtime.h>
#include <hip/hip_fp16.h>
#include <math.h>

#define D_IN 128
#define D_H  64
#define D_OUT 40
#define S2   64           // padded h2 row stride (halfs) = 128 B aligned rows
#define NEG_SLOPE 0.2f

// ---------------- CSR build ----------------

__global__ void k_count(const int* __restrict__ ei, int E, int N, int* __restrict__ deg) {
    int e = blockIdx.x * blockDim.x + threadIdx.x;
    int EP = E + N;
    if (e >= EP) return;
    int d = (e < E) ? ei[E + e] : (e - E);
    atomicAdd(&deg[d], 1);
}

__global__ __launch_bounds__(256) void k_scan1(const int* __restrict__ deg, int N,
                                               int* __restrict__ offs, int* __restrict__ bsums) {
    int t = threadIdx.x;
    int i = blockIdx.x * 256 + t;
    int lane = t & 63, w = t >> 6;
    int v = (i < N) ? deg[i] : 0;
    int incl = v;
    for (int o = 1; o < 64; o <<= 1) {
        int n = __shfl_up(incl, o);
        if (lane >= o) incl += n;
    }
    __shared__ int wsum[4];
    if (lane == 63) wsum[w] = incl;
    __syncthreads();
    int woff = 0;
    for (int j = 0; j < w; j++) woff += wsum[j];
    if (i < N) offs[i] = woff + incl - v;
    if (t == 255) bsums[blockIdx.x] = woff + incl;
}

__global__ __launch_bounds__(256) void k_scan2(const int* __restrict__ bsums, int nb,
                                               int* __restrict__ boffs) {
    int t = threadIdx.x;
    int lane = t & 63, w = t >> 6;
    int v = (t < nb) ? bsums[t] : 0;
    int incl = v;
    for (int o = 1; o < 64; o <<= 1) {
        int n = __shfl_up(incl, o);
        if (lane >= o) incl += n;
    }
    __shared__ int wsum[4];
    if (lane == 63) wsum[w] = incl;
    __syncthreads();
    int woff = 0;
    for (int j = 0; j < w; j++) woff += wsum[j];
    boffs[t] = woff + incl - v;
}

__global__ __launch_bounds__(256) void k_scan3(int* __restrict__ offs, const int* __restrict__ boffs,
                                               int N, int EP) {
    int i = blockIdx.x * 256 + threadIdx.x;
    if (i < N) offs[i] += boffs[blockIdx.x];
    if (i == 0) offs[N] = EP;
}

// fill CSR: single 8B scatter per edge: ep[slot] = {src, p1}  (R8-proven)
__global__ void k_fill(const int* __restrict__ ei, int E, int N,
                       const int* __restrict__ offs, int* __restrict__ cursor,
                       const float* __restrict__ as1, const float* __restrict__ ad1,
                       int2* __restrict__ ep) {
    int e = blockIdx.x * blockDim.x + threadIdx.x;
    int EP = E + N;
    if (e >= EP) return;
    int s, d;
    if (e < E) { s = ei[e]; d = ei[E + e]; }
    else       { s = e - E; d = e - E; }
    int pos = atomicAdd(&cursor[d], 1);
    int slot = offs[d] + pos;
    float v = as1[s] + ad1[d];
    v = v > 0.f ? v : NEG_SLOPE * v;
    ep[slot] = make_int2(s, __float_as_int(__expf(v)));
}

// ---------------- Layer 1 GEMM: 64x64 tile, 4x4 micro-tile, fused att dots ----

__global__ __launch_bounds__(256, 4) void k_gemm1(const float* __restrict__ x,
                                                  const float* __restrict__ W1,
                                                  const float* __restrict__ att_s,
                                                  const float* __restrict__ att_d,
                                                  int N,
                                                  __half* __restrict__ h1h,
                                                  float* __restrict__ as1,
                                                  float* __restrict__ ad1) {
    __shared__ float Wl[D_IN * D_H];
    __shared__ float xs[64 * 68];
    int t = threadIdx.x;
    for (int i = t * 4; i < D_IN * D_H; i += 1024)
        *(float4*)&Wl[i] = *(const float4*)&W1[i];

    int nodeBase = blockIdx.x * 64;
    int r0 = (t >> 4) * 4;
    int c0 = (t & 15) * 4;
    float acc[4][4] = {};

    for (int half_ = 0; half_ < 2; ++half_) {
        __syncthreads();
        for (int i = 0; i < 4; ++i) {
            int idx = i * 1024 + t * 4;
            int row = idx >> 6, col = idx & 63;
            int node = nodeBase + row;
            float4 v = make_float4(0.f, 0.f, 0.f, 0.f);
            if (node < N) v = *(const float4*)&x[node * D_IN + half_ * 64 + col];
            *(float4*)&xs[row * 68 + col] = v;
        }
        __syncthreads();
#pragma unroll 4
        for (int k4 = 0; k4 < 64; k4 += 4) {
            float4 a[4], w[4];
#pragma unroll
            for (int r = 0; r < 4; ++r) a[r] = *(float4*)&xs[(r0 + r) * 68 + k4];
#pragma unroll
            for (int kk = 0; kk < 4; ++kk) w[kk] = *(float4*)&Wl[(half_ * 64 + k4 + kk) * D_H + c0];
#pragma unroll
            for (int r = 0; r < 4; ++r) {
                const float* av = (const float*)&a[r];
#pragma unroll
                for (int kk = 0; kk < 4; ++kk) {
                    acc[r][0] = fmaf(av[kk], w[kk].x, acc[r][0]);
                    acc[r][1] = fmaf(av[kk], w[kk].y, acc[r][1]);
                    acc[r][2] = fmaf(av[kk], w[kk].z, acc[r][2]);
                    acc[r][3] = fmaf(av[kk], w[kk].w, acc[r][3]);
                }
            }
        }
    }

#pragma unroll
    for (int r = 0; r < 4; ++r) {
        int node = nodeBase + r0 + r;
        if (node < N) {
            union { __half2 h2v[2]; uint2 u; } pk;
            pk.h2v[0] = __floats2half2_rn(acc[r][0], acc[r][1]);
            pk.h2v[1] = __floats2half2_rn(acc[r][2], acc[r][3]);
            *(uint2*)&h1h[(size_t)node * D_H + c0] = pk.u;
        }
    }
    float4 as4 = *(const float4*)&att_s[c0];
    float4 ad4 = *(const float4*)&att_d[c0];
    float ps[4], pd[4];
#pragma unroll
    for (int r = 0; r < 4; ++r) {
        ps[r] = acc[r][0] * as4.x + acc[r][1] * as4.y + acc[r][2] * as4.z + acc[r][3] * as4.w;
        pd[r] = acc[r][0] * ad4.x + acc[r][1] * ad4.y + acc[r][2] * ad4.z + acc[r][3] * ad4.w;
    }
#pragma unroll
    for (int o = 1; o < 16; o <<= 1) {
#pragma unroll
        for (int r = 0; r < 4; ++r) {
            ps[r] += __shfl_xor(ps[r], o);
            pd[r] += __shfl_xor(pd[r], o);
        }
    }
    if ((t & 15) == 0) {
#pragma unroll
        for (int r = 0; r < 4; ++r) {
            int node = nodeBase + r0 + r;
            if (node < N) { as1[node] = ps[r]; ad1[node] = pd[r]; }
        }
    }
}

// ---- Layer 1 aggregation: reg-cached (s,p), shfl-fed gathers, 4x unroll ----

__global__ __launch_bounds__(256) void k_agg1(const int* __restrict__ offs,
                                              const int2* __restrict__ ep,
                                              const __half* __restrict__ h1h,
                                              const float* __restrict__ b1,
                                              int N,
                                              __half* __restrict__ agg1h) {
    int t = threadIdx.x;
    int wave = t >> 6, lane = t & 63;
    int node = blockIdx.x * 4 + wave;
    if (node >= N) return;
    int start = offs[node], end = offs[node + 1];
    int cnt = end - start;

    int sv = 0; float pv = 0.f;
    if (lane < cnt) { int2 v = ep[start + lane]; sv = v.x; pv = __int_as_float(v.y); }
    float ss = pv;
    for (int i = start + 64 + lane; i < end; i += 64) ss += __int_as_float(ep[i].y);
#pragma unroll
    for (int o = 32; o >= 1; o >>= 1) ss += __shfl_xor(ss, o);
    float inv = 1.f / (ss + 1e-16f);

    int g = lane >> 4;
    int l = lane & 15;
    int mainc = cnt < 64 ? cnt : 64;
    float4 A0 = make_float4(0.f, 0.f, 0.f, 0.f);
    float4 A1 = make_float4(0.f, 0.f, 0.f, 0.f);
    float4 A2 = make_float4(0.f, 0.f, 0.f, 0.f);
    float4 A3 = make_float4(0.f, 0.f, 0.f, 0.f);
    for (int j = 0; j < mainc; j += 16) {
        int i0 = j + g, i1 = j + 4 + g, i2 = j + 8 + g, i3 = j + 12 + g;
        bool v0 = i0 < mainc, v1 = i1 < mainc, v2 = i2 < mainc, v3 = i3 < mainc;
        int s0 = __shfl(sv, v0 ? i0 : 0);
        int s1 = __shfl(sv, v1 ? i1 : 0);
        int s2 = __shfl(sv, v2 ? i2 : 0);
        int s3 = __shfl(sv, v3 ? i3 : 0);
        float p0 = __shfl(pv, v0 ? i0 : 0); p0 = v0 ? p0 : 0.f;
        float p1 = __shfl(pv, v1 ? i1 : 0); p1 = v1 ? p1 : 0.f;
        float p2 = __shfl(pv, v2 ? i2 : 0); p2 = v2 ? p2 : 0.f;
        float p3 = __shfl(pv, v3 ? i3 : 0); p3 = v3 ? p3 : 0.f;
        uint2 r0 = *(const uint2*)&h1h[(size_t)s0 * D_H + l * 4];
        uint2 r1 = *(const uint2*)&h1h[(size_t)s1 * D_H + l * 4];
        uint2 r2 = *(const uint2*)&h1h[(size_t)s2 * D_H + l * 4];
        uint2 r3 = *(const uint2*)&h1h[(size_t)s3 * D_H + l * 4];
        float2 a0 = __half22float2(*(__half2*)&r0.x), b0 = __half22float2(*(__half2*)&r0.y);
        float2 a1 = __half22float2(*(__half2*)&r1.x), b1f = __half22float2(*(__half2*)&r1.y);
        float2 a2 = __half22float2(*(__half2*)&r2.x), b2f = __half22float2(*(__half2*)&r2.y);
        float2 a3 = __half22float2(*(__half2*)&r3.x), b3f = __half22float2(*(__half2*)&r3.y);
        A0.x = fmaf(p0, a0.x, A0.x); A0.y = fmaf(p0, a0.y, A0.y);
        A0.z = fmaf(p0, b0.x, A0.z); A0.w = fmaf(p0, b0.y, A0.w);
        A1.x = fmaf(p1, a1.x, A1.x); A1.y = fmaf(p1, a1.y, A1.y);
        A1.z = fmaf(p1, b1f.x, A1.z); A1.w = fmaf(p1, b1f.y, A1.w);
        A2.x = fmaf(p2, a2.x, A2.x); A2.y = fmaf(p2, a2.y, A2.y);
        A2.z = fmaf(p2, b2f.x, A2.z); A2.w = fmaf(p2, b2f.y, A2.w);
        A3.x = fmaf(p3, a3.x, A3.x); A3.y = fmaf(p3, a3.y, A3.y);
        A3.z = fmaf(p3, b3f.x, A3.z); A3.w = fmaf(p3, b3f.y, A3.w);
    }
    for (int j = 64; j < cnt; j += 4) {
        int idx = start + j + g;
        int s = 0; float p = 0.f;
        if (j + g < cnt) { int2 v = ep[idx]; s = v.x; p = __int_as_float(v.y); }
        uint2 r = *(const uint2*)&h1h[(size_t)s * D_H + l * 4];
        float2 a = __half22float2(*(__half2*)&r.x);
        float2 b = __half22float2(*(__half2*)&r.y);
        A0.x = fmaf(p, a.x, A0.x); A0.y = fmaf(p, a.y, A0.y);
        A0.z = fmaf(p, b.x, A0.z); A0.w = fmaf(p, b.y, A0.w);
    }
    A0.x += A1.x + A2.x + A3.x;
    A0.y += A1.y + A2.y + A3.y;
    A0.z += A1.z + A2.z + A3.z;
    A0.w += A1.w + A2.w + A3.w;
#pragma unroll
    for (int o = 16; o <= 32; o <<= 1) {
        A0.x += __shfl_xor(A0.x, o);
        A0.y += __shfl_xor(A0.y, o);
        A0.z += __shfl_xor(A0.z, o);
        A0.w += __shfl_xor(A0.w, o);
    }
    if (g == 0) {
        float4 bv = *(const float4*)&b1[l * 4];
        float rx = fmaf(A0.x, inv, bv.x); rx = rx > 0.f ? rx : 0.f;
        float ry = fmaf(A0.y, inv, bv.y); ry = ry > 0.f ? ry : 0.f;
        float rz = fmaf(A0.z, inv, bv.z); rz = rz > 0.f ? rz : 0.f;
        float rw = fmaf(A0.w, inv, bv.w); rw = rw > 0.f ? rw : 0.f;
        union { __half2 h2v[2]; uint2 u; } pk;
        pk.h2v[0] = __floats2half2_rn(rx, ry);
        pk.h2v[1] = __floats2half2_rn(rz, rw);
        *(uint2*)&agg1h[(size_t)node * D_H + l * 4] = pk.u;
    }
}

// ---- Layer 2 GEMM: 64x40 tile, reads agg1 fp16, writes padded h2 fp16 + dots -

__global__ __launch_bounds__(256, 4) void k_gemm2t(const __half* __restrict__ agg1h,
                                                   const float* __restrict__ W2,
                                                   const float* __restrict__ atts2,
                                                   const float* __restrict__ attd2,
                                                   int N,
                                                   __half* __restrict__ h2h,
                                                   float* __restrict__ as2,
                                                   float* __restrict__ ad2) {
    __shared__ float Wl[D_H * D_OUT];
    __shared__ float xs[64 * 68];
    __shared__ float sps[64][10];
    __shared__ float spd[64][10];
    int t = threadIdx.x;
    for (int i = t * 4; i < D_H * D_OUT; i += 1024)
        *(float4*)&Wl[i] = *(const float4*)&W2[i];

    int nodeBase = blockIdx.x * 64;
    for (int i = 0; i < 4; ++i) {
        int idx = i * 1024 + t * 4;
        int row = idx >> 6, col = idx & 63;
        int node = nodeBase + row;
        float4 v = make_float4(0.f, 0.f, 0.f, 0.f);
        if (node < N) {
            uint2 raw = *(const uint2*)&agg1h[(size_t)node * D_H + col];
            float2 f0 = __half22float2(*(__half2*)&raw.x);
            float2 f1 = __half22float2(*(__half2*)&raw.y);
            v = make_float4(f0.x, f0.y, f1.x, f1.y);
        }
        *(float4*)&xs[row * 68 + col] = v;
    }
    __syncthreads();

    int r0 = (t / 10) * 4;
    int c0 = (t % 10) * 4;
    if (t < 160) {
        float acc[4][4] = {};
#pragma unroll 4
        for (int k4 = 0; k4 < 64; k4 += 4) {
            float4 a[4], w[4];
#pragma unroll
            for (int r = 0; r < 4; ++r) a[r] = *(float4*)&xs[(r0 + r) * 68 + k4];
#pragma unroll
            for (int kk = 0; kk < 4; ++kk) w[kk] = *(float4*)&Wl[(k4 + kk) * D_OUT + c0];
#pragma unroll
            for (int r = 0; r < 4; ++r) {
                const float* av = (const float*)&a[r];
#pragma unroll
                for (int kk = 0; kk < 4; ++kk) {
                    acc[r][0] = fmaf(av[kk], w[kk].x, acc[r][0]);
                    acc[r][1] = fmaf(av[kk], w[kk].y, acc[r][1]);
                    acc[r][2] = fmaf(av[kk], w[kk].z, acc[r][2]);
                    acc[r][3] = fmaf(av[kk], w[kk].w, acc[r][3]);
                }
            }
        }
#pragma unroll
        for (int r = 0; r < 4; ++r) {
            int node = nodeBase + r0 + r;
            if (node < N) {
                union { __half2 h2v[2]; uint2 u; } pk;
                pk.h2v[0] = __floats2half2_rn(acc[r][0], acc[r][1]);
                pk.h2v[1] = __floats2half2_rn(acc[r][2], acc[r][3]);
                *(uint2*)&h2h[(size_t)node * S2 + c0] = pk.u;
            }
        }
        float4 as4 = *(const float4*)&atts2[c0];
        float4 ad4 = *(const float4*)&attd2[c0];
#pragma unroll
        for (int r = 0; r < 4; ++r) {
            sps[r0 + r][t % 10] = acc[r][0] * as4.x + acc[r][1] * as4.y
                                + acc[r][2] * as4.z + acc[r][3] * as4.w;
            spd[r0 + r][t % 10] = acc[r][0] * ad4.x + acc[r][1] * ad4.y
                                + acc[r][2] * ad4.z + acc[r][3] * ad4.w;
        }
    }
    __syncthreads();
    if (t < 64) {
        int node = nodeBase + t;
        if (node < N) {
            float ps = 0.f, pd = 0.f;
#pragma unroll
            for (int j = 0; j < 10; ++j) { ps += sps[t][j]; pd += spd[t][j]; }
            as2[node] = ps; ad2[node] = pd;
        }
    }
}

// ---- Layer 2 aggregation: reg-cached (s,p2), 4x unroll + log_softmax -------

__global__ __launch_bounds__(256) void k_agg2(const int* __restrict__ offs,
                                              const int2* __restrict__ ep,
                                              const float* __restrict__ as2,
                                              const float* __restrict__ ad2,
                                              const __half* __restrict__ h2h,
                                              const float* __restrict__ b2,
                                              int N,
                                              float* __restrict__ out) {
    int t = threadIdx.x;
    int wave = t >> 6, lane = t & 63;
    int node = blockIdx.x * 4 + wave;
    if (node >= N) return;
    int start = offs[node], end = offs[node + 1];
    int cnt = end - start;
    float adn = ad2[node];

    int sv = 0; float pv = 0.f;
    if (lane < cnt) {
        sv = ep[start + lane].x;
        float e = as2[sv] + adn;
        e = e > 0.f ? e : NEG_SLOPE * e;
        pv = __expf(e);
    }
    float ss = pv;
    for (int i = start + 64 + lane; i < end; i += 64) {
        int s = ep[i].x;
        float e = as2[s] + adn;
        e = e > 0.f ? e : NEG_SLOPE * e;
        ss += __expf(e);
    }
#pragma unroll
    for (int o = 32; o >= 1; o >>= 1) ss += __shfl_xor(ss, o);
    float inv = 1.f / (ss + 1e-16f);

    int g = lane >> 4;
    int l = lane & 15;
    int cl = (l < 10 ? l : 9) * 4;
    int mainc = cnt < 64 ? cnt : 64;
    float4 A0 = make_float4(0.f, 0.f, 0.f, 0.f);
    float4 A1 = make_float4(0.f, 0.f, 0.f, 0.f);
    float4 A2 = make_float4(0.f, 0.f, 0.f, 0.f);
    float4 A3 = make_float4(0.f, 0.f, 0.f, 0.f);
    for (int j = 0; j < mainc; j += 16) {
        int i0 = j + g, i1 = j + 4 + g, i2 = j + 8 + g, i3 = j + 12 + g;
        bool v0 = i0 < mainc, v1 = i1 < mainc, v2 = i2 < mainc, v3 = i3 < mainc;
        int s0 = __shfl(sv, v0 ? i0 : 0);
        int s1 = __shfl(sv, v1 ? i1 : 0);
        int s2 = __shfl(sv, v2 ? i2 : 0);
        int s3 = __shfl(sv, v3 ? i3 : 0);
        float p0 = __shfl(pv, v0 ? i0 : 0); p0 = v0 ? p0 : 0.f;
        float p1 = __shfl(pv, v1 ? i1 : 0); p1 = v1 ? p1 : 0.f;
        float p2 = __shfl(pv, v2 ? i2 : 0); p2 = v2 ? p2 : 0.f;
        float p3 = __shfl(pv, v3 ? i3 : 0); p3 = v3 ? p3 : 0.f;
        uint2 r0 = *(const uint2*)&h2h[(size_t)s0 * S2 + cl];
        uint2 r1 = *(const uint2*)&h2h[(size_t)s1 * S2 + cl];
        uint2 r2 = *(const uint2*)&h2h[(size_t)s2 * S2 + cl];
        uint2 r3 = *(const uint2*)&h2h[(size_t)s3 * S2 + cl];
        float2 a0 = __half22float2(*(__half2*)&r0.x), b0 = __half22float2(*(__half2*)&r0.y);
        float2 a1 = __half22float2(*(__half2*)&r1.x), b1f = __half22float2(*(__half2*)&r1.y);
        float2 a2 = __half22float2(*(__half2*)&r2.x), b2f = __half22float2(*(__half2*)&r2.y);
        float2 a3 = __half22float2(*(__half2*)&r3.x), b3f = __half22float2(*(__half2*)&r3.y);
        A0.x = fmaf(p0, a0.x, A0.x); A0.y = fmaf(p0, a0.y, A0.y);
        A0.z = fmaf(p0, b0.x, A0.z); A0.w = fmaf(p0, b0.y, A0.w);
        A1.x = fmaf(p1, a1.x, A1.x); A1.y = fmaf(p1, a1.y, A1.y);
        A1.z = fmaf(p1, b1f.x, A1.z); A1.w = fmaf(p1, b1f.y, A1.w);
        A2.x = fmaf(p2, a2.x, A2.x); A2.y = fmaf(p2, a2.y, A2.y);
        A2.z = fmaf(p2, b2f.x, A2.z); A2.w = fmaf(p2, b2f.y, A2.w);
        A3.x = fmaf(p3, a3.x, A3.x); A3.y = fmaf(p3, a3.y, A3.y);
        A3.z = fmaf(p3, b3f.x, A3.z); A3.w = fmaf(p3, b3f.y, A3.w);
    }
    for (int j = 64; j < cnt; j += 4) {
        int idx = start + j + g;
        int s = 0; float p = 0.f;
        if (j + g < cnt) {
            s = ep[idx].x;
            float e = as2[s] + adn;
            e = e > 0.f ? e : NEG_SLOPE * e;
            p = __expf(e);
        }
        uint2 r = *(const uint2*)&h2h[(size_t)s * S2 + cl];
        float2 a = __half22float2(*(__half2*)&r.x);
        float2 b = __half22float2(*(__half2*)&r.y);
        A0.x = fmaf(p, a.x, A0.x); A0.y = fmaf(p, a.y, A0.y);
        A0.z = fmaf(p, b.x, A0.z); A0.w = fmaf(p, b.y, A0.w);
    }
    A0.x += A1.x + A2.x + A3.x;
    A0.y += A1.y + A2.y + A3.y;
    A0.z += A1.z + A2.z + A3.z;
    A0.w += A1.w + A2.w + A3.w;
#pragma unroll
    for (int o = 16; o <= 32; o <<= 1) {
        A0.x += __shfl_xor(A0.x, o);
        A0.y += __shfl_xor(A0.y, o);
        A0.z += __shfl_xor(A0.z, o);
        A0.w += __shfl_xor(A0.w, o);
    }

    float o0 = -INFINITY, o1 = -INFINITY, o2 = -INFINITY, o3 = -INFINITY;
    if (l < 10) {
        float4 bv = *(const float4*)&b2[l * 4];
        o0 = fmaf(A0.x, inv, bv.x);
        o1 = fmaf(A0.y, inv, bv.y);
        o2 = fmaf(A0.z, inv, bv.z);
        o3 = fmaf(A0.w, inv, bv.w);
    }
    float mm = fmaxf(fmaxf(o0, o1), fmaxf(o2, o3));
#pragma unroll
    for (int o = 1; o < 16; o <<= 1) mm = fmaxf(mm, __shfl_xor(mm, o));
    float ex = 0.f;
    if (l < 10) ex = __expf(o0 - mm) + __expf(o1 - mm) + __expf(o2 - mm) + __expf(o3 - mm);
#pragma unroll
    for (int o = 1; o < 16; o <<= 1) ex += __shfl_xor(ex, o);
    float lse = mm + logf(ex);
    if (g == 0 && l < 10) {
        float4 v = make_float4(o0 - lse, o1 - lse, o2 - lse, o3 - lse);
        *(float4*)&out[(size_t)node * D_OUT + l * 4] = v;
    }
}

// ---------------- launch ----------------

extern "C" void kernel_launch(void* const* d_in, const int* in_sizes, int n_in,
                              void* d_out, int out_size, void* d_ws, size_t ws_size,
                              hipStream_t stream) {
    const float* x     = (const float*)d_in[0];
    const int*   ei    = (const int*)d_in[1];
    const float* W1    = (const float*)d_in[2];
    const float* atts1 = (const float*)d_in[3];
    const float* attd1 = (const float*)d_in[4];
    const float* b1    = (const float*)d_in[5];
    const float* W2    = (const float*)d_in[6];
    const float* atts2 = (const float*)d_in[7];
    const float* attd2 = (const float*)d_in[8];
    const float* b2    = (const float*)d_in[9];
    float* out = (float*)d_out;

    const int N  = in_sizes[0] / D_IN;      // 50000
    const int E  = in_sizes[1] / 2;         // 800000
    const int EP = E + N;
    const int NB = (N + 255) / 256;

    char* pws = (char*)d_ws;
    int* bufA     = (int*)pws;        pws += (size_t)N * 4;        // deg, later as2
    int* bufB     = (int*)pws;        pws += (size_t)N * 4;        // cursor, later ad2
    int* offs     = (int*)pws;        pws += (size_t)(N + 2) * 4;
    int* bsums    = (int*)pws;        pws += (size_t)256 * 4;
    int* boffs    = (int*)pws;        pws += (size_t)256 * 4;
    int2* ep      = (int2*)pws;       pws += (size_t)EP * 8;       // packed {src, p1}
    __half* h1h   = (__half*)pws;     pws += (size_t)N * D_H * 2;
    float* as1    = (float*)pws;      pws += (size_t)N * 4;
    float* ad1    = (float*)pws;      pws += (size_t)N * 4;
    __half* agg1h = (__half*)pws;     pws += (size_t)N * D_H * 2;
    __half* h2h   = (__half*)pws;     pws += (size_t)N * S2 * 2;   // padded rows (128 B)

    int* deg = bufA;
    int* cursor = bufB;
    float* as2 = (float*)bufA;   // deg dead after scan
    float* ad2 = (float*)bufB;   // cursor dead after fill

    hipMemsetAsync(deg, 0, (size_t)2 * N * 4, stream);

    dim3 blk(256);
    dim3 grdE((EP + 255) / 256);
    dim3 grdN((N + 3) / 4);
    dim3 grdT((N + 63) / 64);

    k_count<<<grdE, blk, 0, stream>>>(ei, E, N, deg);
    k_scan1<<<dim3(NB), blk, 0, stream>>>(deg, N, offs, bsums);
    k_scan2<<<dim3(1), blk, 0, stream>>>(bsums, NB, boffs);
    k_scan3<<<dim3(NB), blk, 0, stream>>>(offs, boffs, N, EP);

    k_gemm1<<<grdT, blk, 0, stream>>>(x, W1, atts1, attd1, N, h1h, as1, ad1);
    k_fill<<<grdE, blk, 0, stream>>>(ei, E, N, offs, cursor, as1, ad1, ep);
    k_agg1<<<grdN, blk, 0, stream>>>(offs, ep, h1h, b1, N, agg1h);
    k_gemm2t<<<grdT, blk, 0, stream>>>(agg1h, W2, atts2, attd2, N, h2h, as2, ad2);
    k_agg2<<<grdN, blk, 0, stream>>>(offs, ep, as2, ad2, h2h, b2, N, out);
}

// Round 14
// 249.637 us; speedup vs baseline: 1.0372x; 1.0094x over previous
//
#include <hip/hip_runtime.h>
#include <hip/hip_fp16.h>
#include <math.h>

#define D_IN 128
#define D_H  64
#define D_OUT 40
#define S2   64           // padded h2 row stride (halfs) = 128 B aligned rows
#define NEG_SLOPE 0.2f

// ---------------- CSR scan (count fused into gemm1) ----------------

__global__ __launch_bounds__(256) void k_scan1(const int* __restrict__ deg, int N,
                                               int* __restrict__ offs, int* __restrict__ bsums) {
    int t = threadIdx.x;
    int i = blockIdx.x * 256 + t;
    int lane = t & 63, w = t >> 6;
    int v = (i < N) ? deg[i] : 0;
    int incl = v;
    for (int o = 1; o < 64; o <<= 1) {
        int n = __shfl_up(incl, o);
        if (lane >= o) incl += n;
    }
    __shared__ int wsum[4];
    if (lane == 63) wsum[w] = incl;
    __syncthreads();
    int woff = 0;
    for (int j = 0; j < w; j++) woff += wsum[j];
    if (i < N) offs[i] = woff + incl - v;   // block-local exclusive
    if (t == 255) bsums[blockIdx.x] = woff + incl;
}

__global__ __launch_bounds__(256) void k_scan2(const int* __restrict__ bsums, int nb,
                                               int* __restrict__ boffs) {
    int t = threadIdx.x;
    int lane = t & 63, w = t >> 6;
    int v = (t < nb) ? bsums[t] : 0;
    int incl = v;
    for (int o = 1; o < 64; o <<= 1) {
        int n = __shfl_up(incl, o);
        if (lane >= o) incl += n;
    }
    __shared__ int wsum[4];
    if (lane == 63) wsum[w] = incl;
    __syncthreads();
    int woff = 0;
    for (int j = 0; j < w; j++) woff += wsum[j];
    boffs[t] = woff + incl - v;
}

// fill CSR: single 8B scatter per edge: ep[slot] = {src, p1}; final offset =
// offs[d] + boffs[d>>8] (scan3 folded in)
__global__ void k_fill(const int* __restrict__ ei, int E, int N,
                       const int* __restrict__ offs, const int* __restrict__ boffs,
                       int* __restrict__ cursor,
                       const float* __restrict__ as1, const float* __restrict__ ad1,
                       int2* __restrict__ ep) {
    int e = blockIdx.x * blockDim.x + threadIdx.x;
    int EP = E + N;
    if (e >= EP) return;
    int s, d;
    if (e < E) { s = ei[e]; d = ei[E + e]; }
    else       { s = e - E; d = e - E; }
    int pos = atomicAdd(&cursor[d], 1);
    int slot = offs[d] + boffs[d >> 8] + pos;
    float v = as1[s] + ad1[d];
    v = v > 0.f ? v : NEG_SLOPE * v;
    ep[slot] = make_int2(s, __float_as_int(__expf(v)));
}

// ---- Layer 1 GEMM (64x64 tile, 4x4 micro-tile) + fused att dots + edge count

__global__ __launch_bounds__(256, 4) void k_gemm1(const float* __restrict__ x,
                                                  const float* __restrict__ W1,
                                                  const float* __restrict__ att_s,
                                                  const float* __restrict__ att_d,
                                                  int N,
                                                  const int* __restrict__ ei, int E,
                                                  int* __restrict__ deg,
                                                  __half* __restrict__ h1h,
                                                  float* __restrict__ as1,
                                                  float* __restrict__ ad1) {
    __shared__ float Wl[D_IN * D_H];
    __shared__ float xs[64 * 68];
    int t = threadIdx.x;

    // fused k_count: grid-stride over edges; atomics drain under the GEMM
    {
        int EP = E + N;
        int stride = gridDim.x * 256;
        for (int e = blockIdx.x * 256 + t; e < EP; e += stride) {
            int d = (e < E) ? ei[E + e] : (e - E);
            atomicAdd(&deg[d], 1);
        }
    }

    for (int i = t * 4; i < D_IN * D_H; i += 1024)
        *(float4*)&Wl[i] = *(const float4*)&W1[i];

    int nodeBase = blockIdx.x * 64;
    int r0 = (t >> 4) * 4;
    int c0 = (t & 15) * 4;
    float acc[4][4] = {};

    for (int half_ = 0; half_ < 2; ++half_) {
        __syncthreads();
        for (int i = 0; i < 4; ++i) {
            int idx = i * 1024 + t * 4;
            int row = idx >> 6, col = idx & 63;
            int node = nodeBase + row;
            float4 v = make_float4(0.f, 0.f, 0.f, 0.f);
            if (node < N) v = *(const float4*)&x[node * D_IN + half_ * 64 + col];
            *(float4*)&xs[row * 68 + col] = v;
        }
        __syncthreads();
#pragma unroll 4
        for (int k4 = 0; k4 < 64; k4 += 4) {
            float4 a[4], w[4];
#pragma unroll
            for (int r = 0; r < 4; ++r) a[r] = *(float4*)&xs[(r0 + r) * 68 + k4];
#pragma unroll
            for (int kk = 0; kk < 4; ++kk) w[kk] = *(float4*)&Wl[(half_ * 64 + k4 + kk) * D_H + c0];
#pragma unroll
            for (int r = 0; r < 4; ++r) {
                const float* av = (const float*)&a[r];
#pragma unroll
                for (int kk = 0; kk < 4; ++kk) {
                    acc[r][0] = fmaf(av[kk], w[kk].x, acc[r][0]);
                    acc[r][1] = fmaf(av[kk], w[kk].y, acc[r][1]);
                    acc[r][2] = fmaf(av[kk], w[kk].z, acc[r][2]);
                    acc[r][3] = fmaf(av[kk], w[kk].w, acc[r][3]);
                }
            }
        }
    }

#pragma unroll
    for (int r = 0; r < 4; ++r) {
        int node = nodeBase + r0 + r;
        if (node < N) {
            union { __half2 h2v[2]; uint2 u; } pk;
            pk.h2v[0] = __floats2half2_rn(acc[r][0], acc[r][1]);
            pk.h2v[1] = __floats2half2_rn(acc[r][2], acc[r][3]);
            *(uint2*)&h1h[(size_t)node * D_H + c0] = pk.u;
        }
    }
    float4 as4 = *(const float4*)&att_s[c0];
    float4 ad4 = *(const float4*)&att_d[c0];
    float ps[4], pd[4];
#pragma unroll
    for (int r = 0; r < 4; ++r) {
        ps[r] = acc[r][0] * as4.x + acc[r][1] * as4.y + acc[r][2] * as4.z + acc[r][3] * as4.w;
        pd[r] = acc[r][0] * ad4.x + acc[r][1] * ad4.y + acc[r][2] * ad4.z + acc[r][3] * ad4.w;
    }
#pragma unroll
    for (int o = 1; o < 16; o <<= 1) {
#pragma unroll
        for (int r = 0; r < 4; ++r) {
            ps[r] += __shfl_xor(ps[r], o);
            pd[r] += __shfl_xor(pd[r], o);
        }
    }
    if ((t & 15) == 0) {
#pragma unroll
        for (int r = 0; r < 4; ++r) {
            int node = nodeBase + r0 + r;
            if (node < N) { as1[node] = ps[r]; ad1[node] = pd[r]; }
        }
    }
}

// ---- Layer 1 aggregation: reg-cached (s,p), shfl-fed gathers, 4x unroll ----

__global__ __launch_bounds__(256) void k_agg1(const int* __restrict__ offs,
                                              const int* __restrict__ boffs,
                                              const int2* __restrict__ ep,
                                              const __half* __restrict__ h1h,
                                              const float* __restrict__ b1,
                                              int N, int EP,
                                              __half* __restrict__ agg1h) {
    int t = threadIdx.x;
    int wave = t >> 6, lane = t & 63;
    int node = blockIdx.x * 4 + wave;
    if (node >= N) return;
    int start = offs[node] + boffs[node >> 8];
    int np1 = node + 1;
    int end = (np1 == N) ? EP : offs[np1] + boffs[np1 >> 8];
    int cnt = end - start;

    int sv = 0; float pv = 0.f;
    if (lane < cnt) { int2 v = ep[start + lane]; sv = v.x; pv = __int_as_float(v.y); }
    float ss = pv;
    for (int i = start + 64 + lane; i < end; i += 64) ss += __int_as_float(ep[i].y);
#pragma unroll
    for (int o = 32; o >= 1; o >>= 1) ss += __shfl_xor(ss, o);
    float inv = 1.f / (ss + 1e-16f);

    int g = lane >> 4;
    int l = lane & 15;
    int mainc = cnt < 64 ? cnt : 64;
    float4 A0 = make_float4(0.f, 0.f, 0.f, 0.f);
    float4 A1 = make_float4(0.f, 0.f, 0.f, 0.f);
    float4 A2 = make_float4(0.f, 0.f, 0.f, 0.f);
    float4 A3 = make_float4(0.f, 0.f, 0.f, 0.f);
    for (int j = 0; j < mainc; j += 16) {
        int i0 = j + g, i1 = j + 4 + g, i2 = j + 8 + g, i3 = j + 12 + g;
        bool v0 = i0 < mainc, v1 = i1 < mainc, v2 = i2 < mainc, v3 = i3 < mainc;
        int s0 = __shfl(sv, v0 ? i0 : 0);
        int s1 = __shfl(sv, v1 ? i1 : 0);
        int s2 = __shfl(sv, v2 ? i2 : 0);
        int s3 = __shfl(sv, v3 ? i3 : 0);
        float p0 = __shfl(pv, v0 ? i0 : 0); p0 = v0 ? p0 : 0.f;
        float p1 = __shfl(pv, v1 ? i1 : 0); p1 = v1 ? p1 : 0.f;
        float p2 = __shfl(pv, v2 ? i2 : 0); p2 = v2 ? p2 : 0.f;
        float p3 = __shfl(pv, v3 ? i3 : 0); p3 = v3 ? p3 : 0.f;
        uint2 r0 = *(const uint2*)&h1h[(size_t)s0 * D_H + l * 4];
        uint2 r1 = *(const uint2*)&h1h[(size_t)s1 * D_H + l * 4];
        uint2 r2 = *(const uint2*)&h1h[(size_t)s2 * D_H + l * 4];
        uint2 r3 = *(const uint2*)&h1h[(size_t)s3 * D_H + l * 4];
        float2 a0 = __half22float2(*(__half2*)&r0.x), b0 = __half22float2(*(__half2*)&r0.y);
        float2 a1 = __half22float2(*(__half2*)&r1.x), b1f = __half22float2(*(__half2*)&r1.y);
        float2 a2 = __half22float2(*(__half2*)&r2.x), b2f = __half22float2(*(__half2*)&r2.y);
        float2 a3 = __half22float2(*(__half2*)&r3.x), b3f = __half22float2(*(__half2*)&r3.y);
        A0.x = fmaf(p0, a0.x, A0.x); A0.y = fmaf(p0, a0.y, A0.y);
        A0.z = fmaf(p0, b0.x, A0.z); A0.w = fmaf(p0, b0.y, A0.w);
        A1.x = fmaf(p1, a1.x, A1.x); A1.y = fmaf(p1, a1.y, A1.y);
        A1.z = fmaf(p1, b1f.x, A1.z); A1.w = fmaf(p1, b1f.y, A1.w);
        A2.x = fmaf(p2, a2.x, A2.x); A2.y = fmaf(p2, a2.y, A2.y);
        A2.z = fmaf(p2, b2f.x, A2.z); A2.w = fmaf(p2, b2f.y, A2.w);
        A3.x = fmaf(p3, a3.x, A3.x); A3.y = fmaf(p3, a3.y, A3.y);
        A3.z = fmaf(p3, b3f.x, A3.z); A3.w = fmaf(p3, b3f.y, A3.w);
    }
    for (int j = 64; j < cnt; j += 4) {
        int idx = start + j + g;
        int s = 0; float p = 0.f;
        if (j + g < cnt) { int2 v = ep[idx]; s = v.x; p = __int_as_float(v.y); }
        uint2 r = *(const uint2*)&h1h[(size_t)s * D_H + l * 4];
        float2 a = __half22float2(*(__half2*)&r.x);
        float2 b = __half22float2(*(__half2*)&r.y);
        A0.x = fmaf(p, a.x, A0.x); A0.y = fmaf(p, a.y, A0.y);
        A0.z = fmaf(p, b.x, A0.z); A0.w = fmaf(p, b.y, A0.w);
    }
    A0.x += A1.x + A2.x + A3.x;
    A0.y += A1.y + A2.y + A3.y;
    A0.z += A1.z + A2.z + A3.z;
    A0.w += A1.w + A2.w + A3.w;
#pragma unroll
    for (int o = 16; o <= 32; o <<= 1) {
        A0.x += __shfl_xor(A0.x, o);
        A0.y += __shfl_xor(A0.y, o);
        A0.z += __shfl_xor(A0.z, o);
        A0.w += __shfl_xor(A0.w, o);
    }
    if (g == 0) {
        float4 bv = *(const float4*)&b1[l * 4];
        float rx = fmaf(A0.x, inv, bv.x); rx = rx > 0.f ? rx : 0.f;
        float ry = fmaf(A0.y, inv, bv.y); ry = ry > 0.f ? ry : 0.f;
        float rz = fmaf(A0.z, inv, bv.z); rz = rz > 0.f ? rz : 0.f;
        float rw = fmaf(A0.w, inv, bv.w); rw = rw > 0.f ? rw : 0.f;
        union { __half2 h2v[2]; uint2 u; } pk;
        pk.h2v[0] = __floats2half2_rn(rx, ry);
        pk.h2v[1] = __floats2half2_rn(rz, rw);
        *(uint2*)&agg1h[(size_t)node * D_H + l * 4] = pk.u;
    }
}

// ---- Layer 2 GEMM: 64x40 tile, reads agg1 fp16, writes padded h2 fp16 + dots -

__global__ __launch_bounds__(256, 4) void k_gemm2t(const __half* __restrict__ agg1h,
                                                   const float* __restrict__ W2,
                                                   const float* __restrict__ atts2,
                                                   const float* __restrict__ attd2,
                                                   int N,
                                                   __half* __restrict__ h2h,
                                                   float* __restrict__ as2,
                                                   float* __restrict__ ad2) {
    __shared__ float Wl[D_H * D_OUT];
    __shared__ float xs[64 * 68];
    __shared__ float sps[64][10];
    __shared__ float spd[64][10];
    int t = threadIdx.x;
    for (int i = t * 4; i < D_H * D_OUT; i += 1024)
        *(float4*)&Wl[i] = *(const float4*)&W2[i];

    int nodeBase = blockIdx.x * 64;
    for (int i = 0; i < 4; ++i) {
        int idx = i * 1024 + t * 4;
        int row = idx >> 6, col = idx & 63;
        int node = nodeBase + row;
        float4 v = make_float4(0.f, 0.f, 0.f, 0.f);
        if (node < N) {
            uint2 raw = *(const uint2*)&agg1h[(size_t)node * D_H + col];
            float2 f0 = __half22float2(*(__half2*)&raw.x);
            float2 f1 = __half22float2(*(__half2*)&raw.y);
            v = make_float4(f0.x, f0.y, f1.x, f1.y);
        }
        *(float4*)&xs[row * 68 + col] = v;
    }
    __syncthreads();

    int r0 = (t / 10) * 4;
    int c0 = (t % 10) * 4;
    if (t < 160) {
        float acc[4][4] = {};
#pragma unroll 4
        for (int k4 = 0; k4 < 64; k4 += 4) {
            float4 a[4], w[4];
#pragma unroll
            for (int r = 0; r < 4; ++r) a[r] = *(float4*)&xs[(r0 + r) * 68 + k4];
#pragma unroll
            for (int kk = 0; kk < 4; ++kk) w[kk] = *(float4*)&Wl[(k4 + kk) * D_OUT + c0];
#pragma unroll
            for (int r = 0; r < 4; ++r) {
                const float* av = (const float*)&a[r];
#pragma unroll
                for (int kk = 0; kk < 4; ++kk) {
                    acc[r][0] = fmaf(av[kk], w[kk].x, acc[r][0]);
                    acc[r][1] = fmaf(av[kk], w[kk].y, acc[r][1]);
                    acc[r][2] = fmaf(av[kk], w[kk].z, acc[r][2]);
                    acc[r][3] = fmaf(av[kk], w[kk].w, acc[r][3]);
                }
            }
        }
#pragma unroll
        for (int r = 0; r < 4; ++r) {
            int node = nodeBase + r0 + r;
            if (node < N) {
                union { __half2 h2v[2]; uint2 u; } pk;
                pk.h2v[0] = __floats2half2_rn(acc[r][0], acc[r][1]);
                pk.h2v[1] = __floats2half2_rn(acc[r][2], acc[r][3]);
                *(uint2*)&h2h[(size_t)node * S2 + c0] = pk.u;
            }
        }
        float4 as4 = *(const float4*)&atts2[c0];
        float4 ad4 = *(const float4*)&attd2[c0];
#pragma unroll
        for (int r = 0; r < 4; ++r) {
            sps[r0 + r][t % 10] = acc[r][0] * as4.x + acc[r][1] * as4.y
                                + acc[r][2] * as4.z + acc[r][3] * as4.w;
            spd[r0 + r][t % 10] = acc[r][0] * ad4.x + acc[r][1] * ad4.y
                                + acc[r][2] * ad4.z + acc[r][3] * ad4.w;
        }
    }
    __syncthreads();
    if (t < 64) {
        int node = nodeBase + t;
        if (node < N) {
            float ps = 0.f, pd = 0.f;
#pragma unroll
            for (int j = 0; j < 10; ++j) { ps += sps[t][j]; pd += spd[t][j]; }
            as2[node] = ps; ad2[node] = pd;
        }
    }
}

// ---- Layer 2 aggregation: reg-cached (s,p2), 4x unroll + log_softmax -------

__global__ __launch_bounds__(256) void k_agg2(const int* __restrict__ offs,
                                              const int* __restrict__ boffs,
                                              const int2* __restrict__ ep,
                                              const float* __restrict__ as2,
                                              const float* __restrict__ ad2,
                                              const __half* __restrict__ h2h,
                                              const float* __restrict__ b2,
                                              int N, int EP,
                                              float* __restrict__ out) {
    int t = threadIdx.x;
    int wave = t >> 6, lane = t & 63;
    int node = blockIdx.x * 4 + wave;
    if (node >= N) return;
    int start = offs[node] + boffs[node >> 8];
    int np1 = node + 1;
    int end = (np1 == N) ? EP : offs[np1] + boffs[np1 >> 8];
    int cnt = end - start;
    float adn = ad2[node];

    int sv = 0; float pv = 0.f;
    if (lane < cnt) {
        sv = ep[start + lane].x;
        float e = as2[sv] + adn;
        e = e > 0.f ? e : NEG_SLOPE * e;
        pv = __expf(e);
    }
    float ss = pv;
    for (int i = start + 64 + lane; i < end; i += 64) {
        int s = ep[i].x;
        float e = as2[s] + adn;
        e = e > 0.f ? e : NEG_SLOPE * e;
        ss += __expf(e);
    }
#pragma unroll
    for (int o = 32; o >= 1; o >>= 1) ss += __shfl_xor(ss, o);
    float inv = 1.f / (ss + 1e-16f);

    int g = lane >> 4;
    int l = lane & 15;
    int cl = (l < 10 ? l : 9) * 4;
    int mainc = cnt < 64 ? cnt : 64;
    float4 A0 = make_float4(0.f, 0.f, 0.f, 0.f);
    float4 A1 = make_float4(0.f, 0.f, 0.f, 0.f);
    float4 A2 = make_float4(0.f, 0.f, 0.f, 0.f);
    float4 A3 = make_float4(0.f, 0.f, 0.f, 0.f);
    for (int j = 0; j < mainc; j += 16) {
        int i0 = j + g, i1 = j + 4 + g, i2 = j + 8 + g, i3 = j + 12 + g;
        bool v0 = i0 < mainc, v1 = i1 < mainc, v2 = i2 < mainc, v3 = i3 < mainc;
        int s0 = __shfl(sv, v0 ? i0 : 0);
        int s1 = __shfl(sv, v1 ? i1 : 0);
        int s2 = __shfl(sv, v2 ? i2 : 0);
        int s3 = __shfl(sv, v3 ? i3 : 0);
        float p0 = __shfl(pv, v0 ? i0 : 0); p0 = v0 ? p0 : 0.f;
        float p1 = __shfl(pv, v1 ? i1 : 0); p1 = v1 ? p1 : 0.f;
        float p2 = __shfl(pv, v2 ? i2 : 0); p2 = v2 ? p2 : 0.f;
        float p3 = __shfl(pv, v3 ? i3 : 0); p3 = v3 ? p3 : 0.f;
        uint2 r0 = *(const uint2*)&h2h[(size_t)s0 * S2 + cl];
        uint2 r1 = *(const uint2*)&h2h[(size_t)s1 * S2 + cl];
        uint2 r2 = *(const uint2*)&h2h[(size_t)s2 * S2 + cl];
        uint2 r3 = *(const uint2*)&h2h[(size_t)s3 * S2 + cl];
        float2 a0 = __half22float2(*(__half2*)&r0.x), b0 = __half22float2(*(__half2*)&r0.y);
        float2 a1 = __half22float2(*(__half2*)&r1.x), b1f = __half22float2(*(__half2*)&r1.y);
        float2 a2 = __half22float2(*(__half2*)&r2.x), b2f = __half22float2(*(__half2*)&r2.y);
        float2 a3 = __half22float2(*(__half2*)&r3.x), b3f = __half22float2(*(__half2*)&r3.y);
        A0.x = fmaf(p0, a0.x, A0.x); A0.y = fmaf(p0, a0.y, A0.y);
        A0.z = fmaf(p0, b0.x, A0.z); A0.w = fmaf(p0, b0.y, A0.w);
        A1.x = fmaf(p1, a1.x, A1.x); A1.y = fmaf(p1, a1.y, A1.y);
        A1.z = fmaf(p1, b1f.x, A1.z); A1.w = fmaf(p1, b1f.y, A1.w);
        A2.x = fmaf(p2, a2.x, A2.x); A2.y = fmaf(p2, a2.y, A2.y);
        A2.z = fmaf(p2, b2f.x, A2.z); A2.w = fmaf(p2, b2f.y, A2.w);
        A3.x = fmaf(p3, a3.x, A3.x); A3.y = fmaf(p3, a3.y, A3.y);
        A3.z = fmaf(p3, b3f.x, A3.z); A3.w = fmaf(p3, b3f.y, A3.w);
    }
    for (int j = 64; j < cnt; j += 4) {
        int idx = start + j + g;
        int s = 0; float p = 0.f;
        if (j + g < cnt) {
            s = ep[idx].x;
            float e = as2[s] + adn;
            e = e > 0.f ? e : NEG_SLOPE * e;
            p = __expf(e);
        }
        uint2 r = *(const uint2*)&h2h[(size_t)s * S2 + cl];
        float2 a = __half22float2(*(__half2*)&r.x);
        float2 b = __half22float2(*(__half2*)&r.y);
        A0.x = fmaf(p, a.x, A0.x); A0.y = fmaf(p, a.y, A0.y);
        A0.z = fmaf(p, b.x, A0.z); A0.w = fmaf(p, b.y, A0.w);
    }
    A0.x += A1.x + A2.x + A3.x;
    A0.y += A1.y + A2.y + A3.y;
    A0.z += A1.z + A2.z + A3.z;
    A0.w += A1.w + A2.w + A3.w;
#pragma unroll
    for (int o = 16; o <= 32; o <<= 1) {
        A0.x += __shfl_xor(A0.x, o);
        A0.y += __shfl_xor(A0.y, o);
        A0.z += __shfl_xor(A0.z, o);
        A0.w += __shfl_xor(A0.w, o);
    }

    float o0 = -INFINITY, o1 = -INFINITY, o2 = -INFINITY, o3 = -INFINITY;
    if (l < 10) {
        float4 bv = *(const float4*)&b2[l * 4];
        o0 = fmaf(A0.x, inv, bv.x);
        o1 = fmaf(A0.y, inv, bv.y);
        o2 = fmaf(A0.z, inv, bv.z);
        o3 = fmaf(A0.w, inv, bv.w);
    }
    float mm = fmaxf(fmaxf(o0, o1), fmaxf(o2, o3));
#pragma unroll
    for (int o = 1; o < 16; o <<= 1) mm = fmaxf(mm, __shfl_xor(mm, o));
    float ex = 0.f;
    if (l < 10) ex = __expf(o0 - mm) + __expf(o1 - mm) + __expf(o2 - mm) + __expf(o3 - mm);
#pragma unroll
    for (int o = 1; o < 16; o <<= 1) ex += __shfl_xor(ex, o);
    float lse = mm + logf(ex);
    if (g == 0 && l < 10) {
        float4 v = make_float4(o0 - lse, o1 - lse, o2 - lse, o3 - lse);
        *(float4*)&out[(size_t)node * D_OUT + l * 4] = v;
    }
}

// ---------------- launch ----------------

extern "C" void kernel_launch(void* const* d_in, const int* in_sizes, int n_in,
                              void* d_out, int out_size, void* d_ws, size_t ws_size,
                              hipStream_t stream) {
    const float* x     = (const float*)d_in[0];
    const int*   ei    = (const int*)d_in[1];
    const float* W1    = (const float*)d_in[2];
    const float* atts1 = (const float*)d_in[3];
    const float* attd1 = (const float*)d_in[4];
    const float* b1    = (const float*)d_in[5];
    const float* W2    = (const float*)d_in[6];
    const float* atts2 = (const float*)d_in[7];
    const float* attd2 = (const float*)d_in[8];
    const float* b2    = (const float*)d_in[9];
    float* out = (float*)d_out;

    const int N  = in_sizes[0] / D_IN;      // 50000
    const int E  = in_sizes[1] / 2;         // 800000
    const int EP = E + N;
    const int NB = (N + 255) / 256;         // 196

    char* pws = (char*)d_ws;
    int* bufA     = (int*)pws;        pws += (size_t)N * 4;        // deg, later as2
    int* bufB     = (int*)pws;        pws += (size_t)N * 4;        // cursor, later ad2
    int* offs     = (int*)pws;        pws += (size_t)(N + 2) * 4;  // block-local exclusive
    int* bsums    = (int*)pws;        pws += (size_t)256 * 4;
    int* boffs    = (int*)pws;        pws += (size_t)256 * 4;
    int2* ep      = (int2*)pws;       pws += (size_t)EP * 8;       // packed {src, p1}
    __half* h1h   = (__half*)pws;     pws += (size_t)N * D_H * 2;
    float* as1    = (float*)pws;      pws += (size_t)N * 4;
    float* ad1    = (float*)pws;      pws += (size_t)N * 4;
    __half* agg1h = (__half*)pws;     pws += (size_t)N * D_H * 2;
    __half* h2h   = (__half*)pws;     pws += (size_t)N * S2 * 2;   // padded rows (128 B)

    int* deg = bufA;
    int* cursor = bufB;
    float* as2 = (float*)bufA;   // deg dead after scan1
    float* ad2 = (float*)bufB;   // cursor dead after fill

    hipMemsetAsync(deg, 0, (size_t)2 * N * 4, stream);   // deg + cursor

    dim3 blk(256);
    dim3 grdE((EP + 255) / 256);
    dim3 grdN((N + 3) / 4);
    dim3 grdT((N + 63) / 64);

    k_gemm1<<<grdT, blk, 0, stream>>>(x, W1, atts1, attd1, N, ei, E, deg, h1h, as1, ad1);
    k_scan1<<<dim3(NB), blk, 0, stream>>>(deg, N, offs, bsums);
    k_scan2<<<dim3(1), blk, 0, stream>>>(bsums, NB, boffs);
    k_fill<<<grdE, blk, 0, stream>>>(ei, E, N, offs, boffs, cursor, as1, ad1, ep);
    k_agg1<<<grdN, blk, 0, stream>>>(offs, boffs, ep, h1h, b1, N, EP, agg1h);
    k_gemm2t<<<grdT, blk, 0, stream>>>(agg1h, W2, atts2, attd2, N, h2h, as2, ad2);
    k_agg2<<<grdN, blk, 0, stream>>>(offs, boffs, ep, as2, ad2, h2h, b2, N, EP, out);
}

// Round 15
// 248.953 us; speedup vs baseline: 1.0401x; 1.0027x over previous
//
#include <hip/hip_runtime.h>
#include <hip/hip_fp16.h>
#include <math.h>

#define D_IN 128
#define D_H  64
#define D_OUT 40
#define S2   64           // padded h2 row stride (halfs) = 128 B aligned rows
#define NEG_SLOPE 0.2f

// ---------------- CSR scan (count fused into gemm1 tail) ----------------

__global__ __launch_bounds__(256) void k_scan1(const int* __restrict__ deg, int N,
                                               int* __restrict__ offs, int* __restrict__ bsums) {
    int t = threadIdx.x;
    int i = blockIdx.x * 256 + t;
    int lane = t & 63, w = t >> 6;
    int v = (i < N) ? deg[i] : 0;
    int incl = v;
    for (int o = 1; o < 64; o <<= 1) {
        int n = __shfl_up(incl, o);
        if (lane >= o) incl += n;
    }
    __shared__ int wsum[4];
    if (lane == 63) wsum[w] = incl;
    __syncthreads();
    int woff = 0;
    for (int j = 0; j < w; j++) woff += wsum[j];
    if (i < N) offs[i] = woff + incl - v;   // block-local exclusive
    if (t == 255) bsums[blockIdx.x] = woff + incl;
}

__global__ __launch_bounds__(256) void k_scan2(const int* __restrict__ bsums, int nb,
                                               int* __restrict__ boffs) {
    int t = threadIdx.x;
    int lane = t & 63, w = t >> 6;
    int v = (t < nb) ? bsums[t] : 0;
    int incl = v;
    for (int o = 1; o < 64; o <<= 1) {
        int n = __shfl_up(incl, o);
        if (lane >= o) incl += n;
    }
    __shared__ int wsum[4];
    if (lane == 63) wsum[w] = incl;
    __syncthreads();
    int woff = 0;
    for (int j = 0; j < w; j++) woff += wsum[j];
    boffs[t] = woff + incl - v;
}

// fill CSR: single 8B scatter per edge: ep[slot] = {src, p1}; final offset =
// offs[d] + boffs[d>>8] (scan3 folded in)
__global__ void k_fill(const int* __restrict__ ei, int E, int N,
                       const int* __restrict__ offs, const int* __restrict__ boffs,
                       int* __restrict__ cursor,
                       const float* __restrict__ as1, const float* __restrict__ ad1,
                       int2* __restrict__ ep) {
    int e = blockIdx.x * blockDim.x + threadIdx.x;
    int EP = E + N;
    if (e >= EP) return;
    int s, d;
    if (e < E) { s = ei[e]; d = ei[E + e]; }
    else       { s = e - E; d = e - E; }
    int pos = atomicAdd(&cursor[d], 1);
    int slot = offs[d] + boffs[d >> 8] + pos;
    float v = as1[s] + ad1[d];
    v = v > 0.f ? v : NEG_SLOPE * v;
    ep[slot] = make_int2(s, __float_as_int(__expf(v)));
}

// ---- Layer 1 GEMM (64x64 tile, 4x4 micro-tile, half-staged W) + att dots
// ---- + edge count at tail (atomics drain under other blocks' compute)

__global__ __launch_bounds__(256, 4) void k_gemm1(const float* __restrict__ x,
                                                  const float* __restrict__ W1,
                                                  const float* __restrict__ att_s,
                                                  const float* __restrict__ att_d,
                                                  int N,
                                                  const int* __restrict__ ei, int E,
                                                  int* __restrict__ deg,
                                                  __half* __restrict__ h1h,
                                                  float* __restrict__ as1,
                                                  float* __restrict__ ad1) {
    __shared__ float Wl[64 * D_H];       // 16 KB (one k-half at a time)
    __shared__ float xs[64 * 68];        // 17.4 KB  -> 33.4 KB total, 4 blocks/CU
    int t = threadIdx.x;

    int nodeBase = blockIdx.x * 64;
    int r0 = (t >> 4) * 4;
    int c0 = (t & 15) * 4;
    float acc[4][4] = {};

    for (int half_ = 0; half_ < 2; ++half_) {
        __syncthreads();   // protect previous iteration's Wl/xs reads
        for (int i = t * 4; i < 64 * D_H; i += 1024)
            *(float4*)&Wl[i] = *(const float4*)&W1[half_ * 64 * D_H + i];
        for (int i = 0; i < 4; ++i) {
            int idx = i * 1024 + t * 4;
            int row = idx >> 6, col = idx & 63;
            int node = nodeBase + row;
            float4 v = make_float4(0.f, 0.f, 0.f, 0.f);
            if (node < N) v = *(const float4*)&x[node * D_IN + half_ * 64 + col];
            *(float4*)&xs[row * 68 + col] = v;
        }
        __syncthreads();
#pragma unroll 4
        for (int k4 = 0; k4 < 64; k4 += 4) {
            float4 a[4], w[4];
#pragma unroll
            for (int r = 0; r < 4; ++r) a[r] = *(float4*)&xs[(r0 + r) * 68 + k4];
#pragma unroll
            for (int kk = 0; kk < 4; ++kk) w[kk] = *(float4*)&Wl[(k4 + kk) * D_H + c0];
#pragma unroll
            for (int r = 0; r < 4; ++r) {
                const float* av = (const float*)&a[r];
#pragma unroll
                for (int kk = 0; kk < 4; ++kk) {
                    acc[r][0] = fmaf(av[kk], w[kk].x, acc[r][0]);
                    acc[r][1] = fmaf(av[kk], w[kk].y, acc[r][1]);
                    acc[r][2] = fmaf(av[kk], w[kk].z, acc[r][2]);
                    acc[r][3] = fmaf(av[kk], w[kk].w, acc[r][3]);
                }
            }
        }
    }

#pragma unroll
    for (int r = 0; r < 4; ++r) {
        int node = nodeBase + r0 + r;
        if (node < N) {
            union { __half2 h2v[2]; uint2 u; } pk;
            pk.h2v[0] = __floats2half2_rn(acc[r][0], acc[r][1]);
            pk.h2v[1] = __floats2half2_rn(acc[r][2], acc[r][3]);
            *(uint2*)&h1h[(size_t)node * D_H + c0] = pk.u;
        }
    }
    float4 as4 = *(const float4*)&att_s[c0];
    float4 ad4 = *(const float4*)&att_d[c0];
    float ps[4], pd[4];
#pragma unroll
    for (int r = 0; r < 4; ++r) {
        ps[r] = acc[r][0] * as4.x + acc[r][1] * as4.y + acc[r][2] * as4.z + acc[r][3] * as4.w;
        pd[r] = acc[r][0] * ad4.x + acc[r][1] * ad4.y + acc[r][2] * ad4.z + acc[r][3] * ad4.w;
    }
#pragma unroll
    for (int o = 1; o < 16; o <<= 1) {
#pragma unroll
        for (int r = 0; r < 4; ++r) {
            ps[r] += __shfl_xor(ps[r], o);
            pd[r] += __shfl_xor(pd[r], o);
        }
    }
    if ((t & 15) == 0) {
#pragma unroll
        for (int r = 0; r < 4; ++r) {
            int node = nodeBase + r0 + r;
            if (node < N) { as1[node] = ps[r]; ad1[node] = pd[r]; }
        }
    }

    // fused k_count at tail: grid-stride over edges
    {
        int EP = E + N;
        int stride = gridDim.x * 256;
        for (int e = blockIdx.x * 256 + t; e < EP; e += stride) {
            int d = (e < E) ? ei[E + e] : (e - E);
            atomicAdd(&deg[d], 1);
        }
    }
}

// ---- Layer 1 aggregation: reg-cached (s,p), shfl-fed gathers, 4x unroll ----

__global__ __launch_bounds__(256) void k_agg1(const int* __restrict__ offs,
                                              const int* __restrict__ boffs,
                                              const int2* __restrict__ ep,
                                              const __half* __restrict__ h1h,
                                              const float* __restrict__ b1,
                                              int N, int EP,
                                              __half* __restrict__ agg1h) {
    int t = threadIdx.x;
    int wave = t >> 6, lane = t & 63;
    int node = blockIdx.x * 4 + wave;
    if (node >= N) return;
    int start = offs[node] + boffs[node >> 8];
    int np1 = node + 1;
    int end = (np1 == N) ? EP : offs[np1] + boffs[np1 >> 8];
    int cnt = end - start;

    int sv = 0; float pv = 0.f;
    if (lane < cnt) { int2 v = ep[start + lane]; sv = v.x; pv = __int_as_float(v.y); }
    float ss = pv;
    for (int i = start + 64 + lane; i < end; i += 64) ss += __int_as_float(ep[i].y);
#pragma unroll
    for (int o = 32; o >= 1; o >>= 1) ss += __shfl_xor(ss, o);
    float inv = 1.f / (ss + 1e-16f);

    int g = lane >> 4;
    int l = lane & 15;
    int mainc = cnt < 64 ? cnt : 64;
    float4 A0 = make_float4(0.f, 0.f, 0.f, 0.f);
    float4 A1 = make_float4(0.f, 0.f, 0.f, 0.f);
    float4 A2 = make_float4(0.f, 0.f, 0.f, 0.f);
    float4 A3 = make_float4(0.f, 0.f, 0.f, 0.f);
    for (int j = 0; j < mainc; j += 16) {
        int i0 = j + g, i1 = j + 4 + g, i2 = j + 8 + g, i3 = j + 12 + g;
        bool v0 = i0 < mainc, v1 = i1 < mainc, v2 = i2 < mainc, v3 = i3 < mainc;
        int s0 = __shfl(sv, v0 ? i0 : 0);
        int s1 = __shfl(sv, v1 ? i1 : 0);
        int s2 = __shfl(sv, v2 ? i2 : 0);
        int s3 = __shfl(sv, v3 ? i3 : 0);
        float p0 = __shfl(pv, v0 ? i0 : 0); p0 = v0 ? p0 : 0.f;
        float p1 = __shfl(pv, v1 ? i1 : 0); p1 = v1 ? p1 : 0.f;
        float p2 = __shfl(pv, v2 ? i2 : 0); p2 = v2 ? p2 : 0.f;
        float p3 = __shfl(pv, v3 ? i3 : 0); p3 = v3 ? p3 : 0.f;
        uint2 r0 = *(const uint2*)&h1h[(size_t)s0 * D_H + l * 4];
        uint2 r1 = *(const uint2*)&h1h[(size_t)s1 * D_H + l * 4];
        uint2 r2 = *(const uint2*)&h1h[(size_t)s2 * D_H + l * 4];
        uint2 r3 = *(const uint2*)&h1h[(size_t)s3 * D_H + l * 4];
        float2 a0 = __half22float2(*(__half2*)&r0.x), b0 = __half22float2(*(__half2*)&r0.y);
        float2 a1 = __half22float2(*(__half2*)&r1.x), b1f = __half22float2(*(__half2*)&r1.y);
        float2 a2 = __half22float2(*(__half2*)&r2.x), b2f = __half22float2(*(__half2*)&r2.y);
        float2 a3 = __half22float2(*(__half2*)&r3.x), b3f = __half22float2(*(__half2*)&r3.y);
        A0.x = fmaf(p0, a0.x, A0.x); A0.y = fmaf(p0, a0.y, A0.y);
        A0.z = fmaf(p0, b0.x, A0.z); A0.w = fmaf(p0, b0.y, A0.w);
        A1.x = fmaf(p1, a1.x, A1.x); A1.y = fmaf(p1, a1.y, A1.y);
        A1.z = fmaf(p1, b1f.x, A1.z); A1.w = fmaf(p1, b1f.y, A1.w);
        A2.x = fmaf(p2, a2.x, A2.x); A2.y = fmaf(p2, a2.y, A2.y);
        A2.z = fmaf(p2, b2f.x, A2.z); A2.w = fmaf(p2, b2f.y, A2.w);
        A3.x = fmaf(p3, a3.x, A3.x); A3.y = fmaf(p3, a3.y, A3.y);
        A3.z = fmaf(p3, b3f.x, A3.z); A3.w = fmaf(p3, b3f.y, A3.w);
    }
    for (int j = 64; j < cnt; j += 4) {
        int idx = start + j + g;
        int s = 0; float p = 0.f;
        if (j + g < cnt) { int2 v = ep[idx]; s = v.x; p = __int_as_float(v.y); }
        uint2 r = *(const uint2*)&h1h[(size_t)s * D_H + l * 4];
        float2 a = __half22float2(*(__half2*)&r.x);
        float2 b = __half22float2(*(__half2*)&r.y);
        A0.x = fmaf(p, a.x, A0.x); A0.y = fmaf(p, a.y, A0.y);
        A0.z = fmaf(p, b.x, A0.z); A0.w = fmaf(p, b.y, A0.w);
    }
    A0.x += A1.x + A2.x + A3.x;
    A0.y += A1.y + A2.y + A3.y;
    A0.z += A1.z + A2.z + A3.z;
    A0.w += A1.w + A2.w + A3.w;
#pragma unroll
    for (int o = 16; o <= 32; o <<= 1) {
        A0.x += __shfl_xor(A0.x, o);
        A0.y += __shfl_xor(A0.y, o);
        A0.z += __shfl_xor(A0.z, o);
        A0.w += __shfl_xor(A0.w, o);
    }
    if (g == 0) {
        float4 bv = *(const float4*)&b1[l * 4];
        float rx = fmaf(A0.x, inv, bv.x); rx = rx > 0.f ? rx : 0.f;
        float ry = fmaf(A0.y, inv, bv.y); ry = ry > 0.f ? ry : 0.f;
        float rz = fmaf(A0.z, inv, bv.z); rz = rz > 0.f ? rz : 0.f;
        float rw = fmaf(A0.w, inv, bv.w); rw = rw > 0.f ? rw : 0.f;
        union { __half2 h2v[2]; uint2 u; } pk;
        pk.h2v[0] = __floats2half2_rn(rx, ry);
        pk.h2v[1] = __floats2half2_rn(rz, rw);
        *(uint2*)&agg1h[(size_t)node * D_H + l * 4] = pk.u;
    }
}

// ---- Layer 2 GEMM: 64x40 tile, reads agg1 fp16, writes padded h2 fp16 + dots -

__global__ __launch_bounds__(256, 4) void k_gemm2t(const __half* __restrict__ agg1h,
                                                   const float* __restrict__ W2,
                                                   const float* __restrict__ atts2,
                                                   const float* __restrict__ attd2,
                                                   int N,
                                                   __half* __restrict__ h2h,
                                                   float* __restrict__ as2,
                                                   float* __restrict__ ad2) {
    __shared__ float Wl[D_H * D_OUT];
    __shared__ float xs[64 * 68];
    __shared__ float sps[64][10];
    __shared__ float spd[64][10];
    int t = threadIdx.x;
    for (int i = t * 4; i < D_H * D_OUT; i += 1024)
        *(float4*)&Wl[i] = *(const float4*)&W2[i];

    int nodeBase = blockIdx.x * 64;
    for (int i = 0; i < 4; ++i) {
        int idx = i * 1024 + t * 4;
        int row = idx >> 6, col = idx & 63;
        int node = nodeBase + row;
        float4 v = make_float4(0.f, 0.f, 0.f, 0.f);
        if (node < N) {
            uint2 raw = *(const uint2*)&agg1h[(size_t)node * D_H + col];
            float2 f0 = __half22float2(*(__half2*)&raw.x);
            float2 f1 = __half22float2(*(__half2*)&raw.y);
            v = make_float4(f0.x, f0.y, f1.x, f1.y);
        }
        *(float4*)&xs[row * 68 + col] = v;
    }
    __syncthreads();

    int r0 = (t / 10) * 4;
    int c0 = (t % 10) * 4;
    if (t < 160) {
        float acc[4][4] = {};
#pragma unroll 4
        for (int k4 = 0; k4 < 64; k4 += 4) {
            float4 a[4], w[4];
#pragma unroll
            for (int r = 0; r < 4; ++r) a[r] = *(float4*)&xs[(r0 + r) * 68 + k4];
#pragma unroll
            for (int kk = 0; kk < 4; ++kk) w[kk] = *(float4*)&Wl[(k4 + kk) * D_OUT + c0];
#pragma unroll
            for (int r = 0; r < 4; ++r) {
                const float* av = (const float*)&a[r];
#pragma unroll
                for (int kk = 0; kk < 4; ++kk) {
                    acc[r][0] = fmaf(av[kk], w[kk].x, acc[r][0]);
                    acc[r][1] = fmaf(av[kk], w[kk].y, acc[r][1]);
                    acc[r][2] = fmaf(av[kk], w[kk].z, acc[r][2]);
                    acc[r][3] = fmaf(av[kk], w[kk].w, acc[r][3]);
                }
            }
        }
#pragma unroll
        for (int r = 0; r < 4; ++r) {
            int node = nodeBase + r0 + r;
            if (node < N) {
                union { __half2 h2v[2]; uint2 u; } pk;
                pk.h2v[0] = __floats2half2_rn(acc[r][0], acc[r][1]);
                pk.h2v[1] = __floats2half2_rn(acc[r][2], acc[r][3]);
                *(uint2*)&h2h[(size_t)node * S2 + c0] = pk.u;
            }
        }
        float4 as4 = *(const float4*)&atts2[c0];
        float4 ad4 = *(const float4*)&attd2[c0];
#pragma unroll
        for (int r = 0; r < 4; ++r) {
            sps[r0 + r][t % 10] = acc[r][0] * as4.x + acc[r][1] * as4.y
                                + acc[r][2] * as4.z + acc[r][3] * as4.w;
            spd[r0 + r][t % 10] = acc[r][0] * ad4.x + acc[r][1] * ad4.y
                                + acc[r][2] * ad4.z + acc[r][3] * ad4.w;
        }
    }
    __syncthreads();
    if (t < 64) {
        int node = nodeBase + t;
        if (node < N) {
            float ps = 0.f, pd = 0.f;
#pragma unroll
            for (int j = 0; j < 10; ++j) { ps += sps[t][j]; pd += spd[t][j]; }
            as2[node] = ps; ad2[node] = pd;
        }
    }
}

// ---- Layer 2 aggregation: reg-cached (s,p2), 4x unroll + log_softmax -------

__global__ __launch_bounds__(256) void k_agg2(const int* __restrict__ offs,
                                              const int* __restrict__ boffs,
                                              const int2* __restrict__ ep,
                                              const float* __restrict__ as2,
                                              const float* __restrict__ ad2,
                                              const __half* __restrict__ h2h,
                                              const float* __restrict__ b2,
                                              int N, int EP,
                                              float* __restrict__ out) {
    int t = threadIdx.x;
    int wave = t >> 6, lane = t & 63;
    int node = blockIdx.x * 4 + wave;
    if (node >= N) return;
    int start = offs[node] + boffs[node >> 8];
    int np1 = node + 1;
    int end = (np1 == N) ? EP : offs[np1] + boffs[np1 >> 8];
    int cnt = end - start;
    float adn = ad2[node];

    int sv = 0; float pv = 0.f;
    if (lane < cnt) {
        sv = ep[start + lane].x;
        float e = as2[sv] + adn;
        e = e > 0.f ? e : NEG_SLOPE * e;
        pv = __expf(e);
    }
    float ss = pv;
    for (int i = start + 64 + lane; i < end; i += 64) {
        int s = ep[i].x;
        float e = as2[s] + adn;
        e = e > 0.f ? e : NEG_SLOPE * e;
        ss += __expf(e);
    }
#pragma unroll
    for (int o = 32; o >= 1; o >>= 1) ss += __shfl_xor(ss, o);
    float inv = 1.f / (ss + 1e-16f);

    int g = lane >> 4;
    int l = lane & 15;
    int cl = (l < 10 ? l : 9) * 4;
    int mainc = cnt < 64 ? cnt : 64;
    float4 A0 = make_float4(0.f, 0.f, 0.f, 0.f);
    float4 A1 = make_float4(0.f, 0.f, 0.f, 0.f);
    float4 A2 = make_float4(0.f, 0.f, 0.f, 0.f);
    float4 A3 = make_float4(0.f, 0.f, 0.f, 0.f);
    for (int j = 0; j < mainc; j += 16) {
        int i0 = j + g, i1 = j + 4 + g, i2 = j + 8 + g, i3 = j + 12 + g;
        bool v0 = i0 < mainc, v1 = i1 < mainc, v2 = i2 < mainc, v3 = i3 < mainc;
        int s0 = __shfl(sv, v0 ? i0 : 0);
        int s1 = __shfl(sv, v1 ? i1 : 0);
        int s2 = __shfl(sv, v2 ? i2 : 0);
        int s3 = __shfl(sv, v3 ? i3 : 0);
        float p0 = __shfl(pv, v0 ? i0 : 0); p0 = v0 ? p0 : 0.f;
        float p1 = __shfl(pv, v1 ? i1 : 0); p1 = v1 ? p1 : 0.f;
        float p2 = __shfl(pv, v2 ? i2 : 0); p2 = v2 ? p2 : 0.f;
        float p3 = __shfl(pv, v3 ? i3 : 0); p3 = v3 ? p3 : 0.f;
        uint2 r0 = *(const uint2*)&h2h[(size_t)s0 * S2 + cl];
        uint2 r1 = *(const uint2*)&h2h[(size_t)s1 * S2 + cl];
        uint2 r2 = *(const uint2*)&h2h[(size_t)s2 * S2 + cl];
        uint2 r3 = *(const uint2*)&h2h[(size_t)s3 * S2 + cl];
        float2 a0 = __half22float2(*(__half2*)&r0.x), b0 = __half22float2(*(__half2*)&r0.y);
        float2 a1 = __half22float2(*(__half2*)&r1.x), b1f = __half22float2(*(__half2*)&r1.y);
        float2 a2 = __half22float2(*(__half2*)&r2.x), b2f = __half22float2(*(__half2*)&r2.y);
        float2 a3 = __half22float2(*(__half2*)&r3.x), b3f = __half22float2(*(__half2*)&r3.y);
        A0.x = fmaf(p0, a0.x, A0.x); A0.y = fmaf(p0, a0.y, A0.y);
        A0.z = fmaf(p0, b0.x, A0.z); A0.w = fmaf(p0, b0.y, A0.w);
        A1.x = fmaf(p1, a1.x, A1.x); A1.y = fmaf(p1, a1.y, A1.y);
        A1.z = fmaf(p1, b1f.x, A1.z); A1.w = fmaf(p1, b1f.y, A1.w);
        A2.x = fmaf(p2, a2.x, A2.x); A2.y = fmaf(p2, a2.y, A2.y);
        A2.z = fmaf(p2, b2f.x, A2.z); A2.w = fmaf(p2, b2f.y, A2.w);
        A3.x = fmaf(p3, a3.x, A3.x); A3.y = fmaf(p3, a3.y, A3.y);
        A3.z = fmaf(p3, b3f.x, A3.z); A3.w = fmaf(p3, b3f.y, A3.w);
    }
    for (int j = 64; j < cnt; j += 4) {
        int idx = start + j + g;
        int s = 0; float p = 0.f;
        if (j + g < cnt) {
            s = ep[idx].x;
            float e = as2[s] + adn;
            e = e > 0.f ? e : NEG_SLOPE * e;
            p = __expf(e);
        }
        uint2 r = *(const uint2*)&h2h[(size_t)s * S2 + cl];
        float2 a = __half22float2(*(__half2*)&r.x);
        float2 b = __half22float2(*(__half2*)&r.y);
        A0.x = fmaf(p, a.x, A0.x); A0.y = fmaf(p, a.y, A0.y);
        A0.z = fmaf(p, b.x, A0.z); A0.w = fmaf(p, b.y, A0.w);
    }
    A0.x += A1.x + A2.x + A3.x;
    A0.y += A1.y + A2.y + A3.y;
    A0.z += A1.z + A2.z + A3.z;
    A0.w += A1.w + A2.w + A3.w;
#pragma unroll
    for (int o = 16; o <= 32; o <<= 1) {
        A0.x += __shfl_xor(A0.x, o);
        A0.y += __shfl_xor(A0.y, o);
        A0.z += __shfl_xor(A0.z, o);
        A0.w += __shfl_xor(A0.w, o);
    }

    float o0 = -INFINITY, o1 = -INFINITY, o2 = -INFINITY, o3 = -INFINITY;
    if (l < 10) {
        float4 bv = *(const float4*)&b2[l * 4];
        o0 = fmaf(A0.x, inv, bv.x);
        o1 = fmaf(A0.y, inv, bv.y);
        o2 = fmaf(A0.z, inv, bv.z);
        o3 = fmaf(A0.w, inv, bv.w);
    }
    float mm = fmaxf(fmaxf(o0, o1), fmaxf(o2, o3));
#pragma unroll
    for (int o = 1; o < 16; o <<= 1) mm = fmaxf(mm, __shfl_xor(mm, o));
    float ex = 0.f;
    if (l < 10) ex = __expf(o0 - mm) + __expf(o1 - mm) + __expf(o2 - mm) + __expf(o3 - mm);
#pragma unroll
    for (int o = 1; o < 16; o <<= 1) ex += __shfl_xor(ex, o);
    float lse = mm + logf(ex);
    if (g == 0 && l < 10) {
        float4 v = make_float4(o0 - lse, o1 - lse, o2 - lse, o3 - lse);
        *(float4*)&out[(size_t)node * D_OUT + l * 4] = v;
    }
}

// ---------------- launch ----------------

extern "C" void kernel_launch(void* const* d_in, const int* in_sizes, int n_in,
                              void* d_out, int out_size, void* d_ws, size_t ws_size,
                              hipStream_t stream) {
    const float* x     = (const float*)d_in[0];
    const int*   ei    = (const int*)d_in[1];
    const float* W1    = (const float*)d_in[2];
    const float* atts1 = (const float*)d_in[3];
    const float* attd1 = (const float*)d_in[4];
    const float* b1    = (const float*)d_in[5];
    const float* W2    = (const float*)d_in[6];
    const float* atts2 = (const float*)d_in[7];
    const float* attd2 = (const float*)d_in[8];
    const float* b2    = (const float*)d_in[9];
    float* out = (float*)d_out;

    const int N  = in_sizes[0] / D_IN;      // 50000
    const int E  = in_sizes[1] / 2;         // 800000
    const int EP = E + N;
    const int NB = (N + 255) / 256;         // 196

    char* pws = (char*)d_ws;
    int* bufA     = (int*)pws;        pws += (size_t)N * 4;        // deg, later as2
    int* bufB     = (int*)pws;        pws += (size_t)N * 4;        // cursor, later ad2
    int* offs     = (int*)pws;        pws += (size_t)(N + 2) * 4;  // block-local exclusive
    int* bsums    = (int*)pws;        pws += (size_t)256 * 4;
    int* boffs    = (int*)pws;        pws += (size_t)256 * 4;
    int2* ep      = (int2*)pws;       pws += (size_t)EP * 8;       // packed {src, p1}
    __half* h1h   = (__half*)pws;     pws += (size_t)N * D_H * 2;
    float* as1    = (float*)pws;      pws += (size_t)N * 4;
    float* ad1    = (float*)pws;      pws += (size_t)N * 4;
    __half* agg1h = (__half*)pws;     pws += (size_t)N * D_H * 2;
    __half* h2h   = (__half*)pws;     pws += (size_t)N * S2 * 2;   // padded rows (128 B)

    int* deg = bufA;
    int* cursor = bufB;
    float* as2 = (float*)bufA;   // deg dead after scan1
    float* ad2 = (float*)bufB;   // cursor dead after fill

    hipMemsetAsync(deg, 0, (size_t)2 * N * 4, stream);   // deg + cursor

    dim3 blk(256);
    dim3 grdE((EP + 255) / 256);
    dim3 grdN((N + 3) / 4);
    dim3 grdT((N + 63) / 64);

    k_gemm1<<<grdT, blk, 0, stream>>>(x, W1, atts1, attd1, N, ei, E, deg, h1h, as1, ad1);
    k_scan1<<<dim3(NB), blk, 0, stream>>>(deg, N, offs, bsums);
    k_scan2<<<dim3(1), blk, 0, stream>>>(bsums, NB, boffs);
    k_fill<<<grdE, blk, 0, stream>>>(ei, E, N, offs, boffs, cursor, as1, ad1, ep);
    k_agg1<<<grdN, blk, 0, stream>>>(offs, boffs, ep, h1h, b1, N, EP, agg1h);
    k_gemm2t<<<grdT, blk, 0, stream>>>(agg1h, W2, atts2, attd2, N, h2h, as2, ad2);
    k_agg2<<<grdN, blk, 0, stream>>>(offs, boffs, ep, as2, ad2, h2h, b2, N, EP, out);
}

// Round 16
// 238.280 us; speedup vs baseline: 1.0867x; 1.0448x over previous
//
#include <hip/hip_runtime.h>
#include <hip/hip_fp16.h>
#include <math.h>

#define D_IN 128
#define D_H  64
#define D_OUT 40
#define S2   64           // padded h2 row stride (halfs) = 128 B aligned rows
#define NEG_SLOPE 0.2f

// ---------------- CSR scan (count fused into gemm1 tail, 8-way split) -------

__global__ __launch_bounds__(256) void k_scan1(const int* __restrict__ deg8, int N,
                                               int* __restrict__ offs, int* __restrict__ bsums) {
    int t = threadIdx.x;
    int i = blockIdx.x * 256 + t;
    int lane = t & 63, w = t >> 6;
    int v = 0;
    if (i < N) {
#pragma unroll
        for (int k = 0; k < 8; ++k) v += deg8[k * N + i];
    }
    int incl = v;
    for (int o = 1; o < 64; o <<= 1) {
        int n = __shfl_up(incl, o);
        if (lane >= o) incl += n;
    }
    __shared__ int wsum[4];
    if (lane == 63) wsum[w] = incl;
    __syncthreads();
    int woff = 0;
    for (int j = 0; j < w; j++) woff += wsum[j];
    if (i < N) offs[i] = woff + incl - v;   // block-local exclusive
    if (t == 255) bsums[blockIdx.x] = woff + incl;
}

__global__ __launch_bounds__(256) void k_scan2(const int* __restrict__ bsums, int nb,
                                               int* __restrict__ boffs) {
    int t = threadIdx.x;
    int lane = t & 63, w = t >> 6;
    int v = (t < nb) ? bsums[t] : 0;
    int incl = v;
    for (int o = 1; o < 64; o <<= 1) {
        int n = __shfl_up(incl, o);
        if (lane >= o) incl += n;
    }
    __shared__ int wsum[4];
    if (lane == 63) wsum[w] = incl;
    __syncthreads();
    int woff = 0;
    for (int j = 0; j < w; j++) woff += wsum[j];
    boffs[t] = woff + incl - v;
}

// fill CSR: single 8B scatter per edge: ep[slot] = {src, p1}; final offset =
// offs[d] + boffs[d>>8] (scan3 folded in)
__global__ void k_fill(const int* __restrict__ ei, int E, int N,
                       const int* __restrict__ offs, const int* __restrict__ boffs,
                       int* __restrict__ cursor,
                       const float* __restrict__ as1, const float* __restrict__ ad1,
                       int2* __restrict__ ep) {
    int e = blockIdx.x * blockDim.x + threadIdx.x;
    int EP = E + N;
    if (e >= EP) return;
    int s, d;
    if (e < E) { s = ei[e]; d = ei[E + e]; }
    else       { s = e - E; d = e - E; }
    int pos = atomicAdd(&cursor[d], 1);
    int slot = offs[d] + boffs[d >> 8] + pos;
    float v = as1[s] + ad1[d];
    v = v > 0.f ? v : NEG_SLOPE * v;
    ep[slot] = make_int2(s, __float_as_int(__expf(v)));
}

// ---- Layer 1 GEMM (64x64 tile, 4x4 micro-tile, half-staged W) + att dots
// ---- + 8-way-split edge count at tail (partition by blockIdx&7 -> per-XCD
// ---- L2 residency of deg lines, ~8x less atomic line migration)

__global__ __launch_bounds__(256, 4) void k_gemm1(const float* __restrict__ x,
                                                  const float* __restrict__ W1,
                                                  const float* __restrict__ att_s,
                                                  const float* __restrict__ att_d,
                                                  int N,
                                                  const int* __restrict__ ei, int E,
                                                  int* __restrict__ deg8,
                                                  __half* __restrict__ h1h,
                                                  float* __restrict__ as1,
                                                  float* __restrict__ ad1) {
    __shared__ float Wl[64 * D_H];       // 16 KB (one k-half at a time)
    __shared__ float xs[64 * 68];        // 17.4 KB
    int t = threadIdx.x;

    int nodeBase = blockIdx.x * 64;
    int r0 = (t >> 4) * 4;
    int c0 = (t & 15) * 4;
    float acc[4][4] = {};

    for (int half_ = 0; half_ < 2; ++half_) {
        __syncthreads();
        for (int i = t * 4; i < 64 * D_H; i += 1024)
            *(float4*)&Wl[i] = *(const float4*)&W1[half_ * 64 * D_H + i];
        for (int i = 0; i < 4; ++i) {
            int idx = i * 1024 + t * 4;
            int row = idx >> 6, col = idx & 63;
            int node = nodeBase + row;
            float4 v = make_float4(0.f, 0.f, 0.f, 0.f);
            if (node < N) v = *(const float4*)&x[node * D_IN + half_ * 64 + col];
            *(float4*)&xs[row * 68 + col] = v;
        }
        __syncthreads();
#pragma unroll 4
        for (int k4 = 0; k4 < 64; k4 += 4) {
            float4 a[4], w[4];
#pragma unroll
            for (int r = 0; r < 4; ++r) a[r] = *(float4*)&xs[(r0 + r) * 68 + k4];
#pragma unroll
            for (int kk = 0; kk < 4; ++kk) w[kk] = *(float4*)&Wl[(k4 + kk) * D_H + c0];
#pragma unroll
            for (int r = 0; r < 4; ++r) {
                const float* av = (const float*)&a[r];
#pragma unroll
                for (int kk = 0; kk < 4; ++kk) {
                    acc[r][0] = fmaf(av[kk], w[kk].x, acc[r][0]);
                    acc[r][1] = fmaf(av[kk], w[kk].y, acc[r][1]);
                    acc[r][2] = fmaf(av[kk], w[kk].z, acc[r][2]);
                    acc[r][3] = fmaf(av[kk], w[kk].w, acc[r][3]);
                }
            }
        }
    }

#pragma unroll
    for (int r = 0; r < 4; ++r) {
        int node = nodeBase + r0 + r;
        if (node < N) {
            union { __half2 h2v[2]; uint2 u; } pk;
            pk.h2v[0] = __floats2half2_rn(acc[r][0], acc[r][1]);
            pk.h2v[1] = __floats2half2_rn(acc[r][2], acc[r][3]);
            *(uint2*)&h1h[(size_t)node * D_H + c0] = pk.u;
        }
    }
    float4 as4 = *(const float4*)&att_s[c0];
    float4 ad4 = *(const float4*)&att_d[c0];
    float ps[4], pd[4];
#pragma unroll
    for (int r = 0; r < 4; ++r) {
        ps[r] = acc[r][0] * as4.x + acc[r][1] * as4.y + acc[r][2] * as4.z + acc[r][3] * as4.w;
        pd[r] = acc[r][0] * ad4.x + acc[r][1] * ad4.y + acc[r][2] * ad4.z + acc[r][3] * ad4.w;
    }
#pragma unroll
    for (int o = 1; o < 16; o <<= 1) {
#pragma unroll
        for (int r = 0; r < 4; ++r) {
            ps[r] += __shfl_xor(ps[r], o);
            pd[r] += __shfl_xor(pd[r], o);
        }
    }
    if ((t & 15) == 0) {
#pragma unroll
        for (int r = 0; r < 4; ++r) {
            int node = nodeBase + r0 + r;
            if (node < N) { as1[node] = ps[r]; ad1[node] = pd[r]; }
        }
    }

    // fused count at tail: 8-way partitioned histogram
    {
        int EP = E + N;
        int stride = gridDim.x * 256;
        int* mydeg = deg8 + (size_t)(blockIdx.x & 7) * N;
        for (int e = blockIdx.x * 256 + t; e < EP; e += stride) {
            int d = (e < E) ? ei[E + e] : (e - E);
            atomicAdd(&mydeg[d], 1);
        }
    }
}

// ---- Layer 1 aggregation: reg-cached (s,p), shfl-fed gathers, 4x unroll ----

__global__ __launch_bounds__(256) void k_agg1(const int* __restrict__ offs,
                                              const int* __restrict__ boffs,
                                              const int2* __restrict__ ep,
                                              const __half* __restrict__ h1h,
                                              const float* __restrict__ b1,
                                              int N, int EP,
                                              __half* __restrict__ agg1h) {
    int t = threadIdx.x;
    int wave = t >> 6, lane = t & 63;
    int node = blockIdx.x * 4 + wave;
    if (node >= N) return;
    int start = offs[node] + boffs[node >> 8];
    int np1 = node + 1;
    int end = (np1 == N) ? EP : offs[np1] + boffs[np1 >> 8];
    int cnt = end - start;

    int sv = 0; float pv = 0.f;
    if (lane < cnt) { int2 v = ep[start + lane]; sv = v.x; pv = __int_as_float(v.y); }
    float ss = pv;
    for (int i = start + 64 + lane; i < end; i += 64) ss += __int_as_float(ep[i].y);
#pragma unroll
    for (int o = 32; o >= 1; o >>= 1) ss += __shfl_xor(ss, o);
    float inv = 1.f / (ss + 1e-16f);

    int g = lane >> 4;
    int l = lane & 15;
    int mainc = cnt < 64 ? cnt : 64;
    float4 A0 = make_float4(0.f, 0.f, 0.f, 0.f);
    float4 A1 = make_float4(0.f, 0.f, 0.f, 0.f);
    float4 A2 = make_float4(0.f, 0.f, 0.f, 0.f);
    float4 A3 = make_float4(0.f, 0.f, 0.f, 0.f);
    for (int j = 0; j < mainc; j += 16) {
        int i0 = j + g, i1 = j + 4 + g, i2 = j + 8 + g, i3 = j + 12 + g;
        bool v0 = i0 < mainc, v1 = i1 < mainc, v2 = i2 < mainc, v3 = i3 < mainc;
        int s0 = __shfl(sv, v0 ? i0 : 0);
        int s1 = __shfl(sv, v1 ? i1 : 0);
        int s2 = __shfl(sv, v2 ? i2 : 0);
        int s3 = __shfl(sv, v3 ? i3 : 0);
        float p0 = __shfl(pv, v0 ? i0 : 0); p0 = v0 ? p0 : 0.f;
        float p1 = __shfl(pv, v1 ? i1 : 0); p1 = v1 ? p1 : 0.f;
        float p2 = __shfl(pv, v2 ? i2 : 0); p2 = v2 ? p2 : 0.f;
        float p3 = __shfl(pv, v3 ? i3 : 0); p3 = v3 ? p3 : 0.f;
        uint2 r0 = *(const uint2*)&h1h[(size_t)s0 * D_H + l * 4];
        uint2 r1 = *(const uint2*)&h1h[(size_t)s1 * D_H + l * 4];
        uint2 r2 = *(const uint2*)&h1h[(size_t)s2 * D_H + l * 4];
        uint2 r3 = *(const uint2*)&h1h[(size_t)s3 * D_H + l * 4];
        float2 a0 = __half22float2(*(__half2*)&r0.x), b0 = __half22float2(*(__half2*)&r0.y);
        float2 a1 = __half22float2(*(__half2*)&r1.x), b1f = __half22float2(*(__half2*)&r1.y);
        float2 a2 = __half22float2(*(__half2*)&r2.x), b2f = __half22float2(*(__half2*)&r2.y);
        float2 a3 = __half22float2(*(__half2*)&r3.x), b3f = __half22float2(*(__half2*)&r3.y);
        A0.x = fmaf(p0, a0.x, A0.x); A0.y = fmaf(p0, a0.y, A0.y);
        A0.z = fmaf(p0, b0.x, A0.z); A0.w = fmaf(p0, b0.y, A0.w);
        A1.x = fmaf(p1, a1.x, A1.x); A1.y = fmaf(p1, a1.y, A1.y);
        A1.z = fmaf(p1, b1f.x, A1.z); A1.w = fmaf(p1, b1f.y, A1.w);
        A2.x = fmaf(p2, a2.x, A2.x); A2.y = fmaf(p2, a2.y, A2.y);
        A2.z = fmaf(p2, b2f.x, A2.z); A2.w = fmaf(p2, b2f.y, A2.w);
        A3.x = fmaf(p3, a3.x, A3.x); A3.y = fmaf(p3, a3.y, A3.y);
        A3.z = fmaf(p3, b3f.x, A3.z); A3.w = fmaf(p3, b3f.y, A3.w);
    }
    for (int j = 64; j < cnt; j += 4) {
        int idx = start + j + g;
        int s = 0; float p = 0.f;
        if (j + g < cnt) { int2 v = ep[idx]; s = v.x; p = __int_as_float(v.y); }
        uint2 r = *(const uint2*)&h1h[(size_t)s * D_H + l * 4];
        float2 a = __half22float2(*(__half2*)&r.x);
        float2 b = __half22float2(*(__half2*)&r.y);
        A0.x = fmaf(p, a.x, A0.x); A0.y = fmaf(p, a.y, A0.y);
        A0.z = fmaf(p, b.x, A0.z); A0.w = fmaf(p, b.y, A0.w);
    }
    A0.x += A1.x + A2.x + A3.x;
    A0.y += A1.y + A2.y + A3.y;
    A0.z += A1.z + A2.z + A3.z;
    A0.w += A1.w + A2.w + A3.w;
#pragma unroll
    for (int o = 16; o <= 32; o <<= 1) {
        A0.x += __shfl_xor(A0.x, o);
        A0.y += __shfl_xor(A0.y, o);
        A0.z += __shfl_xor(A0.z, o);
        A0.w += __shfl_xor(A0.w, o);
    }
    if (g == 0) {
        float4 bv = *(const float4*)&b1[l * 4];
        float rx = fmaf(A0.x, inv, bv.x); rx = rx > 0.f ? rx : 0.f;
        float ry = fmaf(A0.y, inv, bv.y); ry = ry > 0.f ? ry : 0.f;
        float rz = fmaf(A0.z, inv, bv.z); rz = rz > 0.f ? rz : 0.f;
        float rw = fmaf(A0.w, inv, bv.w); rw = rw > 0.f ? rw : 0.f;
        union { __half2 h2v[2]; uint2 u; } pk;
        pk.h2v[0] = __floats2half2_rn(rx, ry);
        pk.h2v[1] = __floats2half2_rn(rz, rw);
        *(uint2*)&agg1h[(size_t)node * D_H + l * 4] = pk.u;
    }
}

// ---- Layer 2 GEMM: 64x40 tile, reads agg1 fp16, writes padded h2 fp16 + dots -

__global__ __launch_bounds__(256, 4) void k_gemm2t(const __half* __restrict__ agg1h,
                                                   const float* __restrict__ W2,
                                                   const float* __restrict__ atts2,
                                                   const float* __restrict__ attd2,
                                                   int N,
                                                   __half* __restrict__ h2h,
                                                   float* __restrict__ as2,
                                                   float* __restrict__ ad2) {
    __shared__ float Wl[D_H * D_OUT];
    __shared__ float xs[64 * 68];
    __shared__ float sps[64][10];
    __shared__ float spd[64][10];
    int t = threadIdx.x;
    for (int i = t * 4; i < D_H * D_OUT; i += 1024)
        *(float4*)&Wl[i] = *(const float4*)&W2[i];

    int nodeBase = blockIdx.x * 64;
    for (int i = 0; i < 4; ++i) {
        int idx = i * 1024 + t * 4;
        int row = idx >> 6, col = idx & 63;
        int node = nodeBase + row;
        float4 v = make_float4(0.f, 0.f, 0.f, 0.f);
        if (node < N) {
            uint2 raw = *(const uint2*)&agg1h[(size_t)node * D_H + col];
            float2 f0 = __half22float2(*(__half2*)&raw.x);
            float2 f1 = __half22float2(*(__half2*)&raw.y);
            v = make_float4(f0.x, f0.y, f1.x, f1.y);
        }
        *(float4*)&xs[row * 68 + col] = v;
    }
    __syncthreads();

    int r0 = (t / 10) * 4;
    int c0 = (t % 10) * 4;
    if (t < 160) {
        float acc[4][4] = {};
#pragma unroll 4
        for (int k4 = 0; k4 < 64; k4 += 4) {
            float4 a[4], w[4];
#pragma unroll
            for (int r = 0; r < 4; ++r) a[r] = *(float4*)&xs[(r0 + r) * 68 + k4];
#pragma unroll
            for (int kk = 0; kk < 4; ++kk) w[kk] = *(float4*)&Wl[(k4 + kk) * D_OUT + c0];
#pragma unroll
            for (int r = 0; r < 4; ++r) {
                const float* av = (const float*)&a[r];
#pragma unroll
                for (int kk = 0; kk < 4; ++kk) {
                    acc[r][0] = fmaf(av[kk], w[kk].x, acc[r][0]);
                    acc[r][1] = fmaf(av[kk], w[kk].y, acc[r][1]);
                    acc[r][2] = fmaf(av[kk], w[kk].z, acc[r][2]);
                    acc[r][3] = fmaf(av[kk], w[kk].w, acc[r][3]);
                }
            }
        }
#pragma unroll
        for (int r = 0; r < 4; ++r) {
            int node = nodeBase + r0 + r;
            if (node < N) {
                union { __half2 h2v[2]; uint2 u; } pk;
                pk.h2v[0] = __floats2half2_rn(acc[r][0], acc[r][1]);
                pk.h2v[1] = __floats2half2_rn(acc[r][2], acc[r][3]);
                *(uint2*)&h2h[(size_t)node * S2 + c0] = pk.u;
            }
        }
        float4 as4 = *(const float4*)&atts2[c0];
        float4 ad4 = *(const float4*)&attd2[c0];
#pragma unroll
        for (int r = 0; r < 4; ++r) {
            sps[r0 + r][t % 10] = acc[r][0] * as4.x + acc[r][1] * as4.y
                                + acc[r][2] * as4.z + acc[r][3] * as4.w;
            spd[r0 + r][t % 10] = acc[r][0] * ad4.x + acc[r][1] * ad4.y
                                + acc[r][2] * ad4.z + acc[r][3] * ad4.w;
        }
    }
    __syncthreads();
    if (t < 64) {
        int node = nodeBase + t;
        if (node < N) {
            float ps = 0.f, pd = 0.f;
#pragma unroll
            for (int j = 0; j < 10; ++j) { ps += sps[t][j]; pd += spd[t][j]; }
            as2[node] = ps; ad2[node] = pd;
        }
    }
}

// ---- Layer 2 aggregation: reg-cached (s,p2), 4x unroll + log_softmax -------

__global__ __launch_bounds__(256) void k_agg2(const int* __restrict__ offs,
                                              const int* __restrict__ boffs,
                                              const int2* __restrict__ ep,
                                              const float* __restrict__ as2,
                                              const float* __restrict__ ad2,
                                              const __half* __restrict__ h2h,
                                              const float* __restrict__ b2,
                                              int N, int EP,
                                              float* __restrict__ out) {
    int t = threadIdx.x;
    int wave = t >> 6, lane = t & 63;
    int node = blockIdx.x * 4 + wave;
    if (node >= N) return;
    int start = offs[node] + boffs[node >> 8];
    int np1 = node + 1;
    int end = (np1 == N) ? EP : offs[np1] + boffs[np1 >> 8];
    int cnt = end - start;
    float adn = ad2[node];

    int sv = 0; float pv = 0.f;
    if (lane < cnt) {
        sv = ep[start + lane].x;
        float e = as2[sv] + adn;
        e = e > 0.f ? e : NEG_SLOPE * e;
        pv = __expf(e);
    }
    float ss = pv;
    for (int i = start + 64 + lane; i < end; i += 64) {
        int s = ep[i].x;
        float e = as2[s] + adn;
        e = e > 0.f ? e : NEG_SLOPE * e;
        ss += __expf(e);
    }
#pragma unroll
    for (int o = 32; o >= 1; o >>= 1) ss += __shfl_xor(ss, o);
    float inv = 1.f / (ss + 1e-16f);

    int g = lane >> 4;
    int l = lane & 15;
    int cl = (l < 10 ? l : 9) * 4;
    int mainc = cnt < 64 ? cnt : 64;
    float4 A0 = make_float4(0.f, 0.f, 0.f, 0.f);
    float4 A1 = make_float4(0.f, 0.f, 0.f, 0.f);
    float4 A2 = make_float4(0.f, 0.f, 0.f, 0.f);
    float4 A3 = make_float4(0.f, 0.f, 0.f, 0.f);
    for (int j = 0; j < mainc; j += 16) {
        int i0 = j + g, i1 = j + 4 + g, i2 = j + 8 + g, i3 = j + 12 + g;
        bool v0 = i0 < mainc, v1 = i1 < mainc, v2 = i2 < mainc, v3 = i3 < mainc;
        int s0 = __shfl(sv, v0 ? i0 : 0);
        int s1 = __shfl(sv, v1 ? i1 : 0);
        int s2 = __shfl(sv, v2 ? i2 : 0);
        int s3 = __shfl(sv, v3 ? i3 : 0);
        float p0 = __shfl(pv, v0 ? i0 : 0); p0 = v0 ? p0 : 0.f;
        float p1 = __shfl(pv, v1 ? i1 : 0); p1 = v1 ? p1 : 0.f;
        float p2 = __shfl(pv, v2 ? i2 : 0); p2 = v2 ? p2 : 0.f;
        float p3 = __shfl(pv, v3 ? i3 : 0); p3 = v3 ? p3 : 0.f;
        uint2 r0 = *(const uint2*)&h2h[(size_t)s0 * S2 + cl];
        uint2 r1 = *(const uint2*)&h2h[(size_t)s1 * S2 + cl];
        uint2 r2 = *(const uint2*)&h2h[(size_t)s2 * S2 + cl];
        uint2 r3 = *(const uint2*)&h2h[(size_t)s3 * S2 + cl];
        float2 a0 = __half22float2(*(__half2*)&r0.x), b0 = __half22float2(*(__half2*)&r0.y);
        float2 a1 = __half22float2(*(__half2*)&r1.x), b1f = __half22float2(*(__half2*)&r1.y);
        float2 a2 = __half22float2(*(__half2*)&r2.x), b2f = __half22float2(*(__half2*)&r2.y);
        float2 a3 = __half22float2(*(__half2*)&r3.x), b3f = __half22float2(*(__half2*)&r3.y);
        A0.x = fmaf(p0, a0.x, A0.x); A0.y = fmaf(p0, a0.y, A0.y);
        A0.z = fmaf(p0, b0.x, A0.z); A0.w = fmaf(p0, b0.y, A0.w);
        A1.x = fmaf(p1, a1.x, A1.x); A1.y = fmaf(p1, a1.y, A1.y);
        A1.z = fmaf(p1, b1f.x, A1.z); A1.w = fmaf(p1, b1f.y, A1.w);
        A2.x = fmaf(p2, a2.x, A2.x); A2.y = fmaf(p2, a2.y, A2.y);
        A2.z = fmaf(p2, b2f.x, A2.z); A2.w = fmaf(p2, b2f.y, A2.w);
        A3.x = fmaf(p3, a3.x, A3.x); A3.y = fmaf(p3, a3.y, A3.y);
        A3.z = fmaf(p3, b3f.x, A3.z); A3.w = fmaf(p3, b3f.y, A3.w);
    }
    for (int j = 64; j < cnt; j += 4) {
        int idx = start + j + g;
        int s = 0; float p = 0.f;
        if (j + g < cnt) {
            s = ep[idx].x;
            float e = as2[s] + adn;
            e = e > 0.f ? e : NEG_SLOPE * e;
            p = __expf(e);
        }
        uint2 r = *(const uint2*)&h2h[(size_t)s * S2 + cl];
        float2 a = __half22float2(*(__half2*)&r.x);
        float2 b = __half22float2(*(__half2*)&r.y);
        A0.x = fmaf(p, a.x, A0.x); A0.y = fmaf(p, a.y, A0.y);
        A0.z = fmaf(p, b.x, A0.z); A0.w = fmaf(p, b.y, A0.w);
    }
    A0.x += A1.x + A2.x + A3.x;
    A0.y += A1.y + A2.y + A3.y;
    A0.z += A1.z + A2.z + A3.z;
    A0.w += A1.w + A2.w + A3.w;
#pragma unroll
    for (int o = 16; o <= 32; o <<= 1) {
        A0.x += __shfl_xor(A0.x, o);
        A0.y += __shfl_xor(A0.y, o);
        A0.z += __shfl_xor(A0.z, o);
        A0.w += __shfl_xor(A0.w, o);
    }

    float o0 = -INFINITY, o1 = -INFINITY, o2 = -INFINITY, o3 = -INFINITY;
    if (l < 10) {
        float4 bv = *(const float4*)&b2[l * 4];
        o0 = fmaf(A0.x, inv, bv.x);
        o1 = fmaf(A0.y, inv, bv.y);
        o2 = fmaf(A0.z, inv, bv.z);
        o3 = fmaf(A0.w, inv, bv.w);
    }
    float mm = fmaxf(fmaxf(o0, o1), fmaxf(o2, o3));
#pragma unroll
    for (int o = 1; o < 16; o <<= 1) mm = fmaxf(mm, __shfl_xor(mm, o));
    float ex = 0.f;
    if (l < 10) ex = __expf(o0 - mm) + __expf(o1 - mm) + __expf(o2 - mm) + __expf(o3 - mm);
#pragma unroll
    for (int o = 1; o < 16; o <<= 1) ex += __shfl_xor(ex, o);
    float lse = mm + logf(ex);
    if (g == 0 && l < 10) {
        float4 v = make_float4(o0 - lse, o1 - lse, o2 - lse, o3 - lse);
        *(float4*)&out[(size_t)node * D_OUT + l * 4] = v;
    }
}

// ---------------- launch ----------------

extern "C" void kernel_launch(void* const* d_in, const int* in_sizes, int n_in,
                              void* d_out, int out_size, void* d_ws, size_t ws_size,
                              hipStream_t stream) {
    const float* x     = (const float*)d_in[0];
    const int*   ei    = (const int*)d_in[1];
    const float* W1    = (const float*)d_in[2];
    const float* atts1 = (const float*)d_in[3];
    const float* attd1 = (const float*)d_in[4];
    const float* b1    = (const float*)d_in[5];
    const float* W2    = (const float*)d_in[6];
    const float* atts2 = (const float*)d_in[7];
    const float* attd2 = (const float*)d_in[8];
    const float* b2    = (const float*)d_in[9];
    float* out = (float*)d_out;

    const int N  = in_sizes[0] / D_IN;      // 50000
    const int E  = in_sizes[1] / 2;         // 800000
    const int EP = E + N;
    const int NB = (N + 255) / 256;         // 196

    char* pws = (char*)d_ws;
    int* deg8     = (int*)pws;        pws += (size_t)8 * N * 4;    // 8-way histogram; [0..N) reused as as2
    int* bufB     = (int*)pws;        pws += (size_t)N * 4;        // cursor, later ad2
    int* offs     = (int*)pws;        pws += (size_t)(N + 2) * 4;  // block-local exclusive
    int* bsums    = (int*)pws;        pws += (size_t)256 * 4;
    int* boffs    = (int*)pws;        pws += (size_t)256 * 4;
    int2* ep      = (int2*)pws;       pws += (size_t)EP * 8;       // packed {src, p1}
    __half* h1h   = (__half*)pws;     pws += (size_t)N * D_H * 2;
    float* as1    = (float*)pws;      pws += (size_t)N * 4;
    float* ad1    = (float*)pws;      pws += (size_t)N * 4;
    __half* agg1h = (__half*)pws;     pws += (size_t)N * D_H * 2;
    __half* h2h   = (__half*)pws;     pws += (size_t)N * S2 * 2;   // padded rows (128 B)

    int* cursor = bufB;
    float* as2 = (float*)deg8;   // deg8 dead after scan1
    float* ad2 = (float*)bufB;   // cursor dead after fill

    hipMemsetAsync(deg8, 0, (size_t)9 * N * 4, stream);   // deg8 (8N) + cursor (N, adjacent)

    dim3 blk(256);
    dim3 grdE((EP + 255) / 256);
    dim3 grdN((N + 3) / 4);
    dim3 grdT((N + 63) / 64);

    k_gemm1<<<grdT, blk, 0, stream>>>(x, W1, atts1, attd1, N, ei, E, deg8, h1h, as1, ad1);
    k_scan1<<<dim3(NB), blk, 0, stream>>>(deg8, N, offs, bsums);
    k_scan2<<<dim3(1), blk, 0, stream>>>(bsums, NB, boffs);
    k_fill<<<grdE, blk, 0, stream>>>(ei, E, N, offs, boffs, cursor, as1, ad1, ep);
    k_agg1<<<grdN, blk, 0, stream>>>(offs, boffs, ep, h1h, b1, N, EP, agg1h);
    k_gemm2t<<<grdT, blk, 0, stream>>>(agg1h, W2, atts2, attd2, N, h2h, as2, ad2);
    k_agg2<<<grdN, blk, 0, stream>>>(offs, boffs, ep, as2, ad2, h2h, b2, N, EP, out);
}